// Round 3
// baseline (3052.006 us; speedup 1.0000x reference)
//
#include <hip/hip_runtime.h>

// ---------------------------------------------------------------------------
// MemMambaBlock on MI355X.  B=4 T=2048 D=1024 D_INNER=2048 D_STATE=128
// NHEADS=32 HEADDIM=64 D_CONV=4 POOL=64 SUMDIM=256 d_in_proj=4384
// Precision: 6-term 3-way-bf16-split MFMA (~f32-exact) for in_proj/out_proj/
// score1 (score ORDERING is discrete); f64 for conv/norms/score head;
// f32 register-resident wave-synchronous sequential scan (matches reference
// f32 recurrence associativity); plain bf16 MFMA for q/gate (smooth paths).
// ---------------------------------------------------------------------------

using u16 = unsigned short;
using bf16x8 = __attribute__((ext_vector_type(8))) short;
using f32x4  = __attribute__((ext_vector_type(4))) float;

#define DEV __device__ __forceinline__

static constexpr int Bb = 4, T = 2048, D = 1024;
static constexpr int DIN = 2048, DST = 128, NH = 32;
static constexpr int DPROJ = 4384;          // 2*DIN + 2*DST + NH
static constexpr int CCH = 2304;            // DIN + 2*DST (conv channels)
static constexpr int ROWS = Bb * T;         // 8192

DEV float bf2f(u16 h) { union { unsigned int u; float f; } v; v.u = ((unsigned int)h) << 16; return v.f; }
DEV u16 f2bf(float f) { union { float f; unsigned int u; } v; v.f = f; unsigned int r = v.u + 0x7fffu + ((v.u >> 16) & 1u); return (u16)(r >> 16); }
DEV double sigd(double x) { return 1.0 / (1.0 + exp(-x)); }

__global__ void diag_kernel(float* o, float v) { if (threadIdx.x == 0) o[0] = v; }
__global__ void zerod_kernel(double* p, int n) { if ((int)threadIdx.x < n) p[threadIdx.x] = 0.0; }

// ------------------------------------------------------------- rmsnorm(x)
__global__ __launch_bounds__(256) void rms_x_kernel(const float* __restrict__ x, const float* __restrict__ w,
                                                    float* __restrict__ u) {
    long row = blockIdx.x; int tid = threadIdx.x;
    const float* xr = x + row * D;
    float4 xv = *(const float4*)(xr + tid * 4);
    double ss = (double)xv.x * xv.x + (double)xv.y * xv.y + (double)xv.z * xv.z + (double)xv.w * xv.w;
    for (int off = 1; off < 64; off <<= 1) ss += __shfl_xor(ss, off);
    __shared__ double tmp[4];
    if ((tid & 63) == 0) tmp[tid >> 6] = ss;
    __syncthreads();
    double tot = tmp[0] + tmp[1] + tmp[2] + tmp[3];
    double scale = 1.0 / sqrt(tot / (double)D + 1e-4);
    float4 wv = *(const float4*)(w + tid * 4);
    long base = row * D + tid * 4;
    u[base + 0] = (float)((double)xv.x * scale * (double)wv.x);
    u[base + 1] = (float)((double)xv.y * scale * (double)wv.y);
    u[base + 2] = (float)((double)xv.z * scale * (double)wv.z);
    u[base + 3] = (float)((double)xv.w * scale * (double)wv.w);
}

// ----------------------------------------------------------------- GEMM
// C[M][N] = A[M][K] @ Bt[N][K]^T.  f32 sources, on-the-fly bf16 split into
// NP planes staged in LDS.  NP=3: 6-term product (~f32-exact).  NP=1: plain.
// MODE 0: in_proj epilogue (split zx into bufZ / bufX / dt,dA)
// MODE 1: relu -> sch          MODE 2: y = x + C -> outy + concat
// MODE 3: -> qbuf              MODE 4: outy += sigmoid(C)*retr*rmask
template <int NP>
DEV void stage_one(u16* s0, u16* s1, u16* s2, const float* __restrict__ src, long ld,
                   int row0, int lastrow, int k0, int tid) {
    int r = tid >> 1, c0 = (tid & 1) << 4;
    long rg = row0 + r; if (rg > lastrow) rg = lastrow;
    const float* p = src + rg * ld + k0 + c0;
    int base = r * 32 + c0;
#pragma unroll
    for (int q = 0; q < 4; q++) {
        float4 v4 = *(const float4*)(p + q * 4);
        float vv[4] = { v4.x, v4.y, v4.z, v4.w };
#pragma unroll
        for (int j = 0; j < 4; j++) {
            float xv = vv[j];
            u16 h = f2bf(xv);
            s0[base + q * 4 + j] = h;
            if constexpr (NP == 3) {
                float r1 = xv - bf2f(h);
                u16 m = f2bf(r1);
                s1[base + q * 4 + j] = m;
                float r2 = r1 - bf2f(m);
                s2[base + q * 4 + j] = f2bf(r2);
            }
        }
    }
}

template <int NP, int MODE>
__global__ __launch_bounds__(256) void gemm_f32(
    const float* __restrict__ A, long lda,
    const float* __restrict__ B, long ldb,
    int M, int N, int K,
    float* __restrict__ out0, float* __restrict__ out1,
    const float* __restrict__ aux0, const float* __restrict__ aux1,
    float* __restrict__ dtb, float* __restrict__ dab) {
    __shared__ __align__(16) u16 sm[NP * 2 * 4096];
    u16* As[3]; u16* Bs[3];
#pragma unroll
    for (int p = 0; p < NP; p++) { As[p] = sm + p * 4096; Bs[p] = sm + (NP + p) * 4096; }
    int tid = threadIdx.x, lane = tid & 63, wid = tid >> 6;
    int wr = wid >> 1, wc = wid & 1;
    int tM = blockIdx.y * 128, tN = blockIdx.x * 128;

    f32x4 acc[4][4];
#pragma unroll
    for (int i = 0; i < 4; i++)
#pragma unroll
        for (int j = 0; j < 4; j++) acc[i][j] = f32x4{0.f, 0.f, 0.f, 0.f};

    int nsteps = K / 32;
    for (int kt = 0; kt < nsteps; ++kt) {
        int k0 = kt * 32;
        __syncthreads();
        stage_one<NP>(As[0], NP == 3 ? As[1] : nullptr, NP == 3 ? As[2] : nullptr, A, lda, tM, M - 1, k0, tid);
        stage_one<NP>(Bs[0], NP == 3 ? Bs[1] : nullptr, NP == 3 ? Bs[2] : nullptr, B, ldb, tN, N - 1, k0, tid);
        __syncthreads();
        int rA = wr * 64 + (lane & 15);
        int rB = wc * 64 + (lane & 15);
        int kk = (lane >> 4) * 8;
        bf16x8 af[NP][4], bfr[NP][4];
#pragma unroll
        for (int p = 0; p < NP; p++)
#pragma unroll
            for (int i = 0; i < 4; i++) {
                af[p][i]  = *(const bf16x8*)(As[p] + (rA + i * 16) * 32 + kk);
                bfr[p][i] = *(const bf16x8*)(Bs[p] + (rB + i * 16) * 32 + kk);
            }
#pragma unroll
        for (int mi = 0; mi < 4; mi++)
#pragma unroll
            for (int ni = 0; ni < 4; ni++) {
                acc[mi][ni] = __builtin_amdgcn_mfma_f32_16x16x32_bf16(af[0][mi], bfr[0][ni], acc[mi][ni], 0, 0, 0);
                if constexpr (NP == 3) {
                    acc[mi][ni] = __builtin_amdgcn_mfma_f32_16x16x32_bf16(af[0][mi], bfr[1][ni], acc[mi][ni], 0, 0, 0);
                    acc[mi][ni] = __builtin_amdgcn_mfma_f32_16x16x32_bf16(af[1][mi], bfr[0][ni], acc[mi][ni], 0, 0, 0);
                    acc[mi][ni] = __builtin_amdgcn_mfma_f32_16x16x32_bf16(af[0][mi], bfr[2][ni], acc[mi][ni], 0, 0, 0);
                    acc[mi][ni] = __builtin_amdgcn_mfma_f32_16x16x32_bf16(af[1][mi], bfr[1][ni], acc[mi][ni], 0, 0, 0);
                    acc[mi][ni] = __builtin_amdgcn_mfma_f32_16x16x32_bf16(af[2][mi], bfr[0][ni], acc[mi][ni], 0, 0, 0);
                }
            }
    }
    int laneh = lane >> 4, lanel = lane & 15;
#pragma unroll
    for (int mi = 0; mi < 4; mi++)
#pragma unroll
        for (int ni = 0; ni < 4; ni++) {
            int col = tN + wc * 64 + ni * 16 + lanel;
            if (col >= N) continue;
#pragma unroll
            for (int r = 0; r < 4; r++) {
                long row = tM + wr * 64 + mi * 16 + laneh * 4 + r;
                float v = acc[mi][ni][r];
                if constexpr (MODE == 0) {
                    if (col < 2048) out0[row * 2048 + col] = v;
                    else if (col < 4352) out1[row * 2304 + (col - 2048)] = v;
                    else {
                        int h = col - 4352;
                        double xx = (double)v + (double)aux0[h];
                        double sp = (xx > 30.0) ? xx : log1p(exp(xx));
                        double a = -exp((double)aux1[h]);
                        dtb[row * NH + h] = (float)sp;
                        dab[row * NH + h] = (float)exp(sp * a);
                    }
                } else if constexpr (MODE == 1) {
                    out0[row * 256 + col] = fmaxf(v, 0.f);
                } else if constexpr (MODE == 2) {
                    float y = aux0[row * 1024 + col] + v;
                    out0[row * 1024 + col] = y;
                    out1[row * 2048 + col] = y;
                } else if constexpr (MODE == 3) {
                    out0[row * 256 + col] = v;
                } else {
                    double g = sigd((double)v);
                    float retr = aux0[row * 2048 + 1024 + col];
                    out0[row * 1024 + col] += (float)(g * (double)retr * (double)aux1[row >> 11]);
                }
            }
        }
}

// ------------------------------------------------- depthwise causal conv4
__global__ __launch_bounds__(256) void conv_kernel(const float* __restrict__ xin, const float* __restrict__ cw,
                                                   const float* __restrict__ cb, float* __restrict__ xbc) {
    int blk = blockIdx.x;
    int ct = blk % 36; int tt = (blk / 36) % 32; int b = blk / (36 * 32);
    int c0 = ct * 64, t0 = tt * 64;
    int tid = threadIdx.x;
    __shared__ float tile[67 * 64];
    for (int i = tid; i < 67 * 64; i += 256) {
        int r = i >> 6, c = i & 63;
        int t = t0 - 3 + r;
        tile[i] = (t >= 0) ? xin[((long)(b * T + t)) * CCH + c0 + c] : 0.f;
    }
    __syncthreads();
    int c = tid & 63; int rb = (tid >> 6) * 16;
    int gc = c0 + c;
    double w0 = cw[gc * 4], w1 = cw[gc * 4 + 1], w2 = cw[gc * 4 + 2], w3 = cw[gc * 4 + 3];
    double bias = cb[gc];
    for (int j = 0; j < 16; j++) {
        int tl = rb + j;
        double a = bias + w0 * (double)tile[tl * 64 + c] + w1 * (double)tile[(tl + 1) * 64 + c]
                        + w2 * (double)tile[(tl + 2) * 64 + c] + w3 * (double)tile[(tl + 3) * 64 + c];
        xbc[((long)(b * T + t0 + tl)) * CCH + gc] = (float)(a * sigd(a));
    }
}

// ------------------------------------------------------------- SSM scan
// Wave-synchronous register scan.  Grid 512 = (b, h, p-quarter), 64 thr.
// Lane l: p = q*16 + (l>>2), owns n = (l&3)*32 .. +32 in 32 VGPRs (f32).
// Per step: prefetch t+1 (global->regs), compute t from LDS tile (no
// barriers, single wave), stage t+1 regs->LDS.  LDS B/C padded 32+4 to keep
// broadcast float4 reads conflict-free.
__global__ __launch_bounds__(64) void scan_kernel(const float* __restrict__ xbc, const float* __restrict__ dtb,
                                                  const float* __restrict__ dab, const float* __restrict__ Dp,
                                                  float* __restrict__ ys) {
    int bx = blockIdx.x;
    int b = bx >> 7, h = (bx >> 2) & 31, q = bx & 3;
    int l = threadIdx.x;
    int pl = l >> 2, sub = l & 3;
    __shared__ __align__(16) float lB[2][144];   // 4 groups of (32 data + 4 pad)
    __shared__ __align__(16) float lC[2][144];
    __shared__ float lX[2][16];

    float hs[32];
#pragma unroll
    for (int j = 0; j < 32; j++) hs[j] = 0.f;
    float sDp = Dp[h];
    long rowbase = (long)b * T;

    // per-lane global pointers
    const float* gB = xbc + rowbase * CCH + 2048 + 2 * l;
    const float* gC = xbc + rowbase * CCH + 2176 + 2 * l;
    const float* gX = xbc + rowbase * CCH + h * 64 + q * 16 + (l & 15);
    const float* gDt = dtb + rowbase * NH + h;
    const float* gDa = dab + rowbase * NH + h;

    int wr2 = 2 * l + ((2 * l) >> 5) * 4;        // swizzled LDS index for this lane's B/C pair

    // ---- preload t = 0
    float2 pB = *(const float2*)gB;
    float2 pC = *(const float2*)gC;
    float pX = (l < 16) ? gX[0] : 0.f;
    float dtc = gDt[0], dac = gDa[0];
    *(float2*)&lB[0][wr2] = pB;
    *(float2*)&lC[0][wr2] = pC;
    if (l < 16) lX[0][l] = pX;

    for (int t = 0; t < T; t++) {
        int cur = t & 1, nxt = cur ^ 1;
        float ndt = 0.f, nda = 0.f;
        if (t + 1 < T) {                          // issue prefetch (latency hides under compute)
            long o = (long)(t + 1) * CCH;
            pB = *(const float2*)(gB + o);
            pC = *(const float2*)(gC + o);
            if (l < 16) pX = gX[o];
            ndt = gDt[(long)(t + 1) * NH];
            nda = gDa[(long)(t + 1) * NH];
        }
        float xt = lX[cur][pl];
        float dtx = dtc * xt;
        const float4* bp = (const float4*)&lB[cur][sub * 36];
        const float4* cp = (const float4*)&lC[cur][sub * 36];
        float y0 = 0.f, y1 = 0.f, y2 = 0.f, y3 = 0.f;
#pragma unroll
        for (int g = 0; g < 8; g++) {
            float4 bv = bp[g];
            float4 cv = cp[g];
            hs[g * 4 + 0] = fmaf(dac, hs[g * 4 + 0], dtx * bv.x); y0 = fmaf(hs[g * 4 + 0], cv.x, y0);
            hs[g * 4 + 1] = fmaf(dac, hs[g * 4 + 1], dtx * bv.y); y1 = fmaf(hs[g * 4 + 1], cv.y, y1);
            hs[g * 4 + 2] = fmaf(dac, hs[g * 4 + 2], dtx * bv.z); y2 = fmaf(hs[g * 4 + 2], cv.z, y2);
            hs[g * 4 + 3] = fmaf(dac, hs[g * 4 + 3], dtx * bv.w); y3 = fmaf(hs[g * 4 + 3], cv.w, y3);
        }
        float y = (y0 + y1) + (y2 + y3);
        y += __shfl_xor(y, 1);
        y += __shfl_xor(y, 2);
        if (sub == 0) ys[(rowbase + t) * DIN + h * 64 + q * 16 + pl] = y + sDp * xt;
        if (t + 1 < T) {                          // stage t+1 into other buffer
            *(float2*)&lB[nxt][wr2] = pB;
            *(float2*)&lC[nxt][wr2] = pC;
            if (l < 16) lX[nxt][l] = pX;
            dtc = ndt; dac = nda;
        }
    }
}

// -------------------------------------------- rmsnorm(y_scan * silu(z)), in-place
__global__ __launch_bounds__(256) void ssmnorm_kernel(float* __restrict__ ys, const float* __restrict__ z,
                                                      const float* __restrict__ w) {
    long row = blockIdx.x; int tid = threadIdx.x;
    float* yr = ys + row * DIN;
    const float* zr = z + row * DIN;
    double v[8]; double ss = 0.0;
#pragma unroll
    for (int j = 0; j < 8; j++) {
        int c = tid * 8 + j;
        double zz = (double)zr[c];
        double val = (double)yr[c] * (zz * sigd(zz));
        v[j] = val; ss += val * val;
    }
    for (int off = 1; off < 64; off <<= 1) ss += __shfl_xor(ss, off);
    __shared__ double tmp[4];
    if ((tid & 63) == 0) tmp[tid >> 6] = ss;
    __syncthreads();
    double tot = tmp[0] + tmp[1] + tmp[2] + tmp[3];
    double scale = 1.0 / sqrt(tot / (double)DIN + 1e-5);
#pragma unroll
    for (int j = 0; j < 8; j++) {
        int c = tid * 8 + j;
        yr[c] = (float)(v[j] * scale * (double)w[c]);
    }
}

// ------------------------------------------------------- score head (2)
__global__ void score2_kernel(const float* __restrict__ sh, const float* __restrict__ w2,
                              float* __restrict__ scores, double* __restrict__ ssum) {
    int row = blockIdx.x * 4 + (threadIdx.x >> 6);
    int lane = threadIdx.x & 63;
    const float* h = sh + (long)row * 256;
    double a = 0.0;
    for (int j = 0; j < 4; j++) a += (double)h[lane * 4 + j] * (double)w2[lane * 4 + j];
    for (int off = 1; off < 64; off <<= 1) a += __shfl_xor(a, off);
    if (lane == 0) {
        double sc = sigd(a);
        scores[row] = (float)sc;
        atomicAdd(&ssum[row >> 11], sc);
    }
}

// ------------------------------------------------ top-64 (stable argsort)
__global__ void top64_kernel(const float* __restrict__ scores, int* __restrict__ tidx, float* __restrict__ tval) {
    int b = blockIdx.x; int tid = threadIdx.x;
    __shared__ float s[T];
    __shared__ float rv[256];
    __shared__ int ri[256];
    for (int i = tid; i < T; i += 256) s[i] = scores[b * T + i];
    for (int k = 0; k < 64; k++) {
        __syncthreads();
        float best = -1e30f; int bi = 1 << 30;
        for (int i = tid; i < T; i += 256) {
            float v = s[i];
            if (v > best || (v == best && i < bi)) { best = v; bi = i; }
        }
        rv[tid] = best; ri[tid] = bi;
        __syncthreads();
        for (int off = 128; off > 0; off >>= 1) {
            if (tid < off) {
                float v2 = rv[tid + off]; int i2 = ri[tid + off];
                if (v2 > rv[tid] || (v2 == rv[tid] && i2 < ri[tid])) { rv[tid] = v2; ri[tid] = i2; }
            }
            __syncthreads();
        }
        if (tid == 0) { tidx[b * 64 + k] = ri[0]; tval[b * 64 + k] = rv[0]; s[ri[0]] = -1e30f; }
    }
}

// ---------------------------------------------------- summaries (64/b)
__global__ __launch_bounds__(256) void summ_kernel(const float* __restrict__ y, const int* __restrict__ tidx,
                                                   const float* __restrict__ wsum, float* __restrict__ summ) {
    int s = blockIdx.x & 63; int b = blockIdx.x >> 6;
    int tid = threadIdx.x;
    __shared__ float yrow[1024];
    int tok = tidx[b * 64 + s];
    long base = ((long)(b * T + tok));
    for (int i = tid; i < 1024; i += 256) yrow[i] = y[base * 1024 + i];
    __syncthreads();
    double acc = 0.0;
    const float* w = wsum + (long)tid * 1024;
    for (int kk = 0; kk < 1024; kk++) acc += (double)yrow[kk] * (double)w[kk];
    summ[((long)(b * 64 + s)) * 256 + tid] = (float)acc;
}

// -------------------------------------------------------- pool update
__global__ void pool_kernel(const float* __restrict__ pin, const float* __restrict__ prin,
                            const int* __restrict__ cin, const float* __restrict__ tval,
                            const float* __restrict__ summ, const double* __restrict__ ssum,
                            float* __restrict__ pout, float* __restrict__ prout,
                            float* __restrict__ cout, float* __restrict__ rmask) {
    int b = blockIdx.x; int tid = threadIdx.x;
    __shared__ float spri[64];
    __shared__ int scount, sact, sslot, srep, srslot;
    for (int i = tid; i < 64 * 256; i += 256) pout[(long)b * 16384 + i] = pin[(long)b * 16384 + i];
    if (tid < 64) spri[tid] = prin[b * 64 + tid];
    if (tid == 0) scount = cin[b];
    __syncthreads();
    for (int s = 0; s < 64; s++) {
        float imp = tval[b * 64 + s];
        bool has = imp > 0.5f;                       // TAU1
        if (tid == 0) {
            sact = 0;
            if (has && scount < 64) { sslot = scount; spri[scount] = imp; scount++; sact = 1; }
        }
        __syncthreads();
        if (sact) pout[((long)(b * 64 + sslot)) * 256 + tid] = summ[((long)(b * 64 + s)) * 256 + tid];
        if (tid < 64) {
            float v = spri[tid]; int idx = tid;
            for (int off = 1; off < 64; off <<= 1) {
                float v2 = __shfl_xor(v, off); int i2 = __shfl_xor(idx, off);
                if (v2 < v || (v2 == v && i2 < idx)) { v = v2; idx = i2; }
            }
            if (tid == 0) {
                srep = 0;
                if (has && scount >= 64 && imp > v) { srep = 1; srslot = idx; spri[idx] = imp; }
            }
        }
        __syncthreads();
        if (srep) pout[((long)(b * 64 + srslot)) * 256 + tid] = summ[((long)(b * 64 + s)) * 256 + tid];
        __syncthreads();
    }
    if (tid < 64) prout[b * 64 + tid] = spri[tid];
    if (tid == 0) {
        cout[b] = (float)scount;
        double mean = ssum[b] / (double)T;
        rmask[b] = (mean > 0.4 && scount > 0) ? 1.f : 0.f;
    }
}

// ------------------------------------------------------------ k,v proj
__global__ __launch_bounds__(256) void kv_kernel(const float* __restrict__ pool, const float* __restrict__ kw,
                                                 const float* __restrict__ vw, float* __restrict__ k,
                                                 float* __restrict__ v) {
    int blk = blockIdx.x; int b = blk >> 6, s = blk & 63; int tid = threadIdx.x;
    __shared__ float pr[256];
    pr[tid] = pool[((long)(b * 64 + s)) * 256 + tid];
    __syncthreads();
    float a = 0.f;
    const float* w = kw + (long)tid * 256;
    for (int j = 0; j < 256; j++) a = fmaf(pr[j], w[j], a);
    k[((long)(b * 64 + s)) * 256 + tid] = a;
    for (int m = 0; m < 4; m++) {
        int o = m * 256 + tid;
        const float* w2 = vw + (long)o * 256;
        float c = 0.f;
        for (int j = 0; j < 256; j++) c = fmaf(pr[j], w2[j], c);
        v[((long)(b * 64 + s)) * 1024 + o] = c;
    }
}

// ----------------------------------------------------- pool attention
__global__ __launch_bounds__(256) void attn_kernel(const float* __restrict__ q, const float* __restrict__ k,
                                                   const float* __restrict__ v, const float* __restrict__ cout,
                                                   float* __restrict__ concat) {
    long row = blockIdx.x;
    int b = (int)(row >> 11);
    int tid = threadIdx.x;
    int cnt = (int)cout[b];
    __shared__ float qs[256], slog[64], sp[64];
    qs[tid] = q[row * 256 + tid];
    __syncthreads();
    int s = tid >> 2, part = tid & 3;
    const float* kr = k + ((long)(b * 64 + s)) * 256 + part * 64;
    float d = 0.f;
    for (int j = 0; j < 64; j++) d = fmaf(qs[part * 64 + j], kr[j], d);
    d += __shfl_xor(d, 1); d += __shfl_xor(d, 2);
    if (part == 0) slog[s] = d * 0.0625f;
    __syncthreads();
    if (tid < 64) {
        float l = (tid < cnt) ? slog[tid] : -1e30f;
        float m = l;
        for (int off = 1; off < 64; off <<= 1) m = fmaxf(m, __shfl_xor(m, off));
        float e = (tid < cnt) ? expf(l - m) : 0.f;
        float su = e;
        for (int off = 1; off < 64; off <<= 1) su += __shfl_xor(su, off);
        sp[tid] = (cnt > 0) ? e / su : 0.f;
    }
    __syncthreads();
    float acc[4] = {0.f, 0.f, 0.f, 0.f};
    for (int s2 = 0; s2 < cnt; s2++) {
        float p = sp[s2];
        const float* vr = v + ((long)(b * 64 + s2)) * 1024 + tid;
        acc[0] = fmaf(p, vr[0], acc[0]);
        acc[1] = fmaf(p, vr[256], acc[1]);
        acc[2] = fmaf(p, vr[512], acc[2]);
        acc[3] = fmaf(p, vr[768], acc[3]);
    }
    for (int j = 0; j < 4; j++) concat[row * 2048 + 1024 + tid + j * 256] = acc[j];
}

// ===========================================================================
extern "C" void kernel_launch(void* const* d_in, const int* in_sizes, int n_in,
                              void* d_out, int out_size, void* d_ws, size_t ws_size,
                              hipStream_t stream) {
    (void)in_sizes; (void)n_in; (void)out_size;
    const float* x       = (const float*)d_in[0];
    const float* pool_in = (const float*)d_in[1];
    const float* pri_in  = (const float*)d_in[2];
    const int*   cnt_in  = (const int*)d_in[3];
    const float* norm_w  = (const float*)d_in[4];
    const float* in_w    = (const float*)d_in[5];
    const float* conv_w  = (const float*)d_in[6];
    const float* conv_b  = (const float*)d_in[7];
    const float* dt_bias = (const float*)d_in[8];
    const float* A_log   = (const float*)d_in[9];
    const float* Dp      = (const float*)d_in[10];
    const float* ssm_w   = (const float*)d_in[11];
    const float* out_w   = (const float*)d_in[12];
    const float* s_w1    = (const float*)d_in[13];
    const float* s_w2    = (const float*)d_in[14];
    const float* summ_w  = (const float*)d_in[15];
    const float* q_w     = (const float*)d_in[16];
    const float* k_w     = (const float*)d_in[17];
    const float* v_w     = (const float*)d_in[18];
    const float* gate_w  = (const float*)d_in[19];

    float* outy    = (float*)d_out;
    float* outpool = outy + (long)ROWS * D;
    float* outpri  = outpool + Bb * 64 * 256;
    float* outcnt  = outpri + Bb * 64;

    char* ws = (char*)d_ws;
    size_t cur = 0;
    auto alloc = [&](size_t bytes) { size_t o = cur; cur += (bytes + 255) / 256 * 256; return o; };

    size_t o_dt   = alloc((size_t)ROWS * NH * 4);
    size_t o_da   = alloc((size_t)ROWS * NH * 4);
    size_t o_sc   = alloc((size_t)ROWS * 4);
    size_t o_ssum = alloc(64);
    size_t o_rmk  = alloc(64);
    size_t o_tidx = alloc(Bb * 64 * 4);
    size_t o_tval = alloc(Bb * 64 * 4);
    size_t o_summ = alloc((size_t)Bb * 64 * 256 * 4);
    size_t o_k    = alloc((size_t)Bb * 64 * 256 * 4);
    size_t o_v    = alloc((size_t)Bb * 64 * 1024 * 4);
    size_t o_RA = alloc((size_t)ROWS * CCH * 4);   // xbc -> concat+sch
    size_t o_RB = alloc((size_t)ROWS * DIN * 4);   // bufZ -> qbuf
    size_t o_RC = alloc((size_t)ROWS * CCH * 4);   // bufX -> yscan/normed (in-place)

    if (ws_size < cur) {   // diagnostic: report ws_size in MB via absmax
        diag_kernel<<<1, 64, 0, stream>>>(outy, 1000.0f + (float)(ws_size >> 20));
        return;
    }

    float* dtb    = (float*)(ws + o_dt);
    float* dab    = (float*)(ws + o_da);
    float* scores = (float*)(ws + o_sc);
    double* ssum  = (double*)(ws + o_ssum);
    float* rmk    = (float*)(ws + o_rmk);
    int*   tidx   = (int*)(ws + o_tidx);
    float* tval   = (float*)(ws + o_tval);
    float* summ   = (float*)(ws + o_summ);
    float* kbuf   = (float*)(ws + o_k);
    float* vbuf   = (float*)(ws + o_v);

    float* xbc    = (float*)(ws + o_RA);
    float* concat = (float*)(ws + o_RA);
    float* sch    = (float*)(ws + o_RA + (size_t)ROWS * DIN * 4);
    float* bufZ   = (float*)(ws + o_RB);
    float* qbuf   = (float*)(ws + o_RB);
    float* bufX   = (float*)(ws + o_RC);
    float* yscan  = (float*)(ws + o_RC);

    // 0. init
    zerod_kernel<<<1, 64, 0, stream>>>(ssum, 4);
    // 1. rmsnorm(x) -> u (stored in outy region of d_out)
    rms_x_kernel<<<ROWS, 256, 0, stream>>>(x, norm_w, outy);
    // 2. in_proj (6-term split): -> bufZ (z), bufX (xBC), dt/dA (f32)
    gemm_f32<3, 0><<<dim3(35, 64), 256, 0, stream>>>(outy, 1024, in_w, 1024, ROWS, DPROJ, 1024,
                                                     bufZ, bufX, dt_bias, A_log, dtb, dab);
    // 3. conv + silu (f64 math) -> xbc (R_A)
    conv_kernel<<<Bb * 32 * 36, 256, 0, stream>>>(bufX, conv_w, conv_b, xbc);
    // 4. scan (register-resident, wave-synchronous) -> yscan (R_C, over dead bufX)
    scan_kernel<<<Bb * NH * 4, 64, 0, stream>>>(xbc, dtb, dab, Dp, yscan);
    // 5. ssm rmsnorm (f64, in-place over yscan)
    ssmnorm_kernel<<<ROWS, 256, 0, stream>>>(yscan, bufZ, ssm_w);
    // 6. out_proj (6-term split) + residual -> outy, concat (R_A, over dead xbc)
    gemm_f32<3, 2><<<dim3(8, 64), 256, 0, stream>>>(yscan, 2048, out_w, 2048, ROWS, 1024, 2048,
                                                    outy, concat, x, nullptr, nullptr, nullptr);
    // 7. score1 (6-term split, relu) -> sch
    gemm_f32<3, 1><<<dim3(2, 64), 256, 0, stream>>>(outy, 1024, s_w1, 1024, ROWS, 256, 1024,
                                                    sch, nullptr, nullptr, nullptr, nullptr, nullptr);
    // 8. score2 (f64) -> scores, ssum
    score2_kernel<<<ROWS / 4, 256, 0, stream>>>(sch, s_w2, scores, ssum);
    // 9. top-64
    top64_kernel<<<Bb, 256, 0, stream>>>(scores, tidx, tval);
    // 10. summaries (f32 y, f64 accum)
    summ_kernel<<<Bb * 64, 256, 0, stream>>>(outy, tidx, summ_w, summ);
    // 11. pool update -> d_out pool/pri/counts + rmask
    pool_kernel<<<Bb, 256, 0, stream>>>(pool_in, pri_in, cnt_in, tval, summ, ssum,
                                        outpool, outpri, outcnt, rmk);
    // 12. k, v
    kv_kernel<<<Bb * 64, 256, 0, stream>>>(outpool, k_w, v_w, kbuf, vbuf);
    // 13. q = y @ q_w^T (plain bf16)
    gemm_f32<1, 3><<<dim3(2, 64), 256, 0, stream>>>(outy, 1024, q_w, 1024, ROWS, 256, 1024,
                                                    qbuf, nullptr, nullptr, nullptr, nullptr, nullptr);
    // 14. attention -> retrieved (f32, concat second half)
    attn_kernel<<<ROWS, 256, 0, stream>>>(qbuf, kbuf, vbuf, outcnt, concat);
    // 15. gate GEMM (plain bf16) + final y update
    gemm_f32<1, 4><<<dim3(8, 64), 256, 0, stream>>>(concat, 2048, gate_w, 2048, ROWS, 1024, 2048,
                                                    outy, nullptr, concat, rmk, nullptr, nullptr);
}

// Round 4
// 2739.539 us; speedup vs baseline: 1.1141x; 1.1141x over previous
//
#include <hip/hip_runtime.h>

// ---------------------------------------------------------------------------
// MemMambaBlock on MI355X.  B=4 T=2048 D=1024 D_INNER=2048 D_STATE=128
// NHEADS=32 HEADDIM=64 D_CONV=4 POOL=64 SUMDIM=256 d_in_proj=4384
// Precision: 6-term 3-way-bf16-split MFMA (~f32-exact) for in_proj/out_proj/
// score1 (score ORDERING is discrete); f64 for conv/norms/score head;
// f32 register-resident wave-synchronous sequential scan (matches reference
// f32 recurrence associativity); plain bf16 MFMA for q/gate (smooth paths).
// Scan v3: 8-deep register-ring software pipeline + 4-slot LDS ring for B/C
// redistribution; all dependencies compiler-visible (no manual vmcnt).
// ---------------------------------------------------------------------------

using u16 = unsigned short;
using bf16x8 = __attribute__((ext_vector_type(8))) short;
using f32x4  = __attribute__((ext_vector_type(4))) float;

#define DEV __device__ __forceinline__

static constexpr int Bb = 4, T = 2048, D = 1024;
static constexpr int DIN = 2048, DST = 128, NH = 32;
static constexpr int DPROJ = 4384;          // 2*DIN + 2*DST + NH
static constexpr int CCH = 2304;            // DIN + 2*DST (conv channels)
static constexpr int ROWS = Bb * T;         // 8192

DEV float bf2f(u16 h) { union { unsigned int u; float f; } v; v.u = ((unsigned int)h) << 16; return v.f; }
DEV u16 f2bf(float f) { union { float f; unsigned int u; } v; v.f = f; unsigned int r = v.u + 0x7fffu + ((v.u >> 16) & 1u); return (u16)(r >> 16); }
DEV double sigd(double x) { return 1.0 / (1.0 + exp(-x)); }

__global__ void diag_kernel(float* o, float v) { if (threadIdx.x == 0) o[0] = v; }
__global__ void zerod_kernel(double* p, int n) { if ((int)threadIdx.x < n) p[threadIdx.x] = 0.0; }

// ------------------------------------------------------------- rmsnorm(x)
__global__ __launch_bounds__(256) void rms_x_kernel(const float* __restrict__ x, const float* __restrict__ w,
                                                    float* __restrict__ u) {
    long row = blockIdx.x; int tid = threadIdx.x;
    const float* xr = x + row * D;
    float4 xv = *(const float4*)(xr + tid * 4);
    double ss = (double)xv.x * xv.x + (double)xv.y * xv.y + (double)xv.z * xv.z + (double)xv.w * xv.w;
    for (int off = 1; off < 64; off <<= 1) ss += __shfl_xor(ss, off);
    __shared__ double tmp[4];
    if ((tid & 63) == 0) tmp[tid >> 6] = ss;
    __syncthreads();
    double tot = tmp[0] + tmp[1] + tmp[2] + tmp[3];
    double scale = 1.0 / sqrt(tot / (double)D + 1e-4);
    float4 wv = *(const float4*)(w + tid * 4);
    long base = row * D + tid * 4;
    u[base + 0] = (float)((double)xv.x * scale * (double)wv.x);
    u[base + 1] = (float)((double)xv.y * scale * (double)wv.y);
    u[base + 2] = (float)((double)xv.z * scale * (double)wv.z);
    u[base + 3] = (float)((double)xv.w * scale * (double)wv.w);
}

// ----------------------------------------------------------------- GEMM
// C[M][N] = A[M][K] @ Bt[N][K]^T.  f32 sources, on-the-fly bf16 split into
// NP planes staged in LDS.  NP=3: 6-term product (~f32-exact).  NP=1: plain.
// MODE 0: in_proj epilogue (split zx into bufZ / bufX / dt,dA)
// MODE 1: relu -> sch          MODE 2: y = x + C -> outy + concat
// MODE 3: -> qbuf              MODE 4: outy += sigmoid(C)*retr*rmask
template <int NP>
DEV void stage_one(u16* s0, u16* s1, u16* s2, const float* __restrict__ src, long ld,
                   int row0, int lastrow, int k0, int tid) {
    int r = tid >> 1, c0 = (tid & 1) << 4;
    long rg = row0 + r; if (rg > lastrow) rg = lastrow;
    const float* p = src + rg * ld + k0 + c0;
    int base = r * 32 + c0;
#pragma unroll
    for (int q = 0; q < 4; q++) {
        float4 v4 = *(const float4*)(p + q * 4);
        float vv[4] = { v4.x, v4.y, v4.z, v4.w };
#pragma unroll
        for (int j = 0; j < 4; j++) {
            float xv = vv[j];
            u16 h = f2bf(xv);
            s0[base + q * 4 + j] = h;
            if constexpr (NP == 3) {
                float r1 = xv - bf2f(h);
                u16 m = f2bf(r1);
                s1[base + q * 4 + j] = m;
                float r2 = r1 - bf2f(m);
                s2[base + q * 4 + j] = f2bf(r2);
            }
        }
    }
}

template <int NP, int MODE>
__global__ __launch_bounds__(256) void gemm_f32(
    const float* __restrict__ A, long lda,
    const float* __restrict__ B, long ldb,
    int M, int N, int K,
    float* __restrict__ out0, float* __restrict__ out1,
    const float* __restrict__ aux0, const float* __restrict__ aux1,
    float* __restrict__ dtb, float* __restrict__ dab) {
    __shared__ __align__(16) u16 sm[NP * 2 * 4096];
    u16* As[3]; u16* Bs[3];
#pragma unroll
    for (int p = 0; p < NP; p++) { As[p] = sm + p * 4096; Bs[p] = sm + (NP + p) * 4096; }
    int tid = threadIdx.x, lane = tid & 63, wid = tid >> 6;
    int wr = wid >> 1, wc = wid & 1;
    int tM = blockIdx.y * 128, tN = blockIdx.x * 128;

    f32x4 acc[4][4];
#pragma unroll
    for (int i = 0; i < 4; i++)
#pragma unroll
        for (int j = 0; j < 4; j++) acc[i][j] = f32x4{0.f, 0.f, 0.f, 0.f};

    int nsteps = K / 32;
    for (int kt = 0; kt < nsteps; ++kt) {
        int k0 = kt * 32;
        __syncthreads();
        stage_one<NP>(As[0], NP == 3 ? As[1] : nullptr, NP == 3 ? As[2] : nullptr, A, lda, tM, M - 1, k0, tid);
        stage_one<NP>(Bs[0], NP == 3 ? Bs[1] : nullptr, NP == 3 ? Bs[2] : nullptr, B, ldb, tN, N - 1, k0, tid);
        __syncthreads();
        int rA = wr * 64 + (lane & 15);
        int rB = wc * 64 + (lane & 15);
        int kk = (lane >> 4) * 8;
        bf16x8 af[NP][4], bfr[NP][4];
#pragma unroll
        for (int p = 0; p < NP; p++)
#pragma unroll
            for (int i = 0; i < 4; i++) {
                af[p][i]  = *(const bf16x8*)(As[p] + (rA + i * 16) * 32 + kk);
                bfr[p][i] = *(const bf16x8*)(Bs[p] + (rB + i * 16) * 32 + kk);
            }
#pragma unroll
        for (int mi = 0; mi < 4; mi++)
#pragma unroll
            for (int ni = 0; ni < 4; ni++) {
                acc[mi][ni] = __builtin_amdgcn_mfma_f32_16x16x32_bf16(af[0][mi], bfr[0][ni], acc[mi][ni], 0, 0, 0);
                if constexpr (NP == 3) {
                    acc[mi][ni] = __builtin_amdgcn_mfma_f32_16x16x32_bf16(af[0][mi], bfr[1][ni], acc[mi][ni], 0, 0, 0);
                    acc[mi][ni] = __builtin_amdgcn_mfma_f32_16x16x32_bf16(af[1][mi], bfr[0][ni], acc[mi][ni], 0, 0, 0);
                    acc[mi][ni] = __builtin_amdgcn_mfma_f32_16x16x32_bf16(af[0][mi], bfr[2][ni], acc[mi][ni], 0, 0, 0);
                    acc[mi][ni] = __builtin_amdgcn_mfma_f32_16x16x32_bf16(af[1][mi], bfr[1][ni], acc[mi][ni], 0, 0, 0);
                    acc[mi][ni] = __builtin_amdgcn_mfma_f32_16x16x32_bf16(af[2][mi], bfr[0][ni], acc[mi][ni], 0, 0, 0);
                }
            }
    }
    int laneh = lane >> 4, lanel = lane & 15;
#pragma unroll
    for (int mi = 0; mi < 4; mi++)
#pragma unroll
        for (int ni = 0; ni < 4; ni++) {
            int col = tN + wc * 64 + ni * 16 + lanel;
            if (col >= N) continue;
#pragma unroll
            for (int r = 0; r < 4; r++) {
                long row = tM + wr * 64 + mi * 16 + laneh * 4 + r;
                float v = acc[mi][ni][r];
                if constexpr (MODE == 0) {
                    if (col < 2048) out0[row * 2048 + col] = v;
                    else if (col < 4352) out1[row * 2304 + (col - 2048)] = v;
                    else {
                        int h = col - 4352;
                        double xx = (double)v + (double)aux0[h];
                        double sp = (xx > 30.0) ? xx : log1p(exp(xx));
                        double a = -exp((double)aux1[h]);
                        dtb[row * NH + h] = (float)sp;
                        dab[row * NH + h] = (float)exp(sp * a);
                    }
                } else if constexpr (MODE == 1) {
                    out0[row * 256 + col] = fmaxf(v, 0.f);
                } else if constexpr (MODE == 2) {
                    float y = aux0[row * 1024 + col] + v;
                    out0[row * 1024 + col] = y;
                    out1[row * 2048 + col] = y;
                } else if constexpr (MODE == 3) {
                    out0[row * 256 + col] = v;
                } else {
                    double g = sigd((double)v);
                    float retr = aux0[row * 2048 + 1024 + col];
                    out0[row * 1024 + col] += (float)(g * (double)retr * (double)aux1[row >> 11]);
                }
            }
        }
}

// ------------------------------------------------- depthwise causal conv4
__global__ __launch_bounds__(256) void conv_kernel(const float* __restrict__ xin, const float* __restrict__ cw,
                                                   const float* __restrict__ cb, float* __restrict__ xbc) {
    int blk = blockIdx.x;
    int ct = blk % 36; int tt = (blk / 36) % 32; int b = blk / (36 * 32);
    int c0 = ct * 64, t0 = tt * 64;
    int tid = threadIdx.x;
    __shared__ float tile[67 * 64];
    for (int i = tid; i < 67 * 64; i += 256) {
        int r = i >> 6, c = i & 63;
        int t = t0 - 3 + r;
        tile[i] = (t >= 0) ? xin[((long)(b * T + t)) * CCH + c0 + c] : 0.f;
    }
    __syncthreads();
    int c = tid & 63; int rb = (tid >> 6) * 16;
    int gc = c0 + c;
    double w0 = cw[gc * 4], w1 = cw[gc * 4 + 1], w2 = cw[gc * 4 + 2], w3 = cw[gc * 4 + 3];
    double bias = cb[gc];
    for (int j = 0; j < 16; j++) {
        int tl = rb + j;
        double a = bias + w0 * (double)tile[tl * 64 + c] + w1 * (double)tile[(tl + 1) * 64 + c]
                        + w2 * (double)tile[(tl + 2) * 64 + c] + w3 * (double)tile[(tl + 3) * 64 + c];
        xbc[((long)(b * T + t0 + tl)) * CCH + gc] = (float)(a * sigd(a));
    }
}

// ------------------------------------------------------------- SSM scan v3
// Wave-synchronous register scan, 8-deep software pipeline.
// Grid 512 = (b, h, p-quarter), 64 threads (1 wave).
// Lane l: p = q*16 + (l>>2), owns n = (l&3)*32 .. +32 in 32 VGPRs (f32).
// Register rings (depth 8, statically indexed via unroll-8 body) hold
// t+1..t+8 prefetches; B/C go through a 4-slot LDS ring whose ds_write
// happens 2 iterations before the ds_read.  All waits are register
// dependences the compiler tracks; single wave => LDS in-order, no barriers.
__global__ __launch_bounds__(64) void scan_kernel(const float* __restrict__ xbc, const float* __restrict__ dtb,
                                                  const float* __restrict__ dab, const float* __restrict__ Dp,
                                                  float* __restrict__ ys) {
    int bx = blockIdx.x;
    int b = bx >> 7, h = (bx >> 2) & 31, q = bx & 3;
    int l = threadIdx.x;
    int pl = l >> 2, sub = l & 3;
    __shared__ __align__(16) float lB[4][144];   // 4 groups of (32 data + 4 pad)
    __shared__ __align__(16) float lC[4][144];

    float hs[32];
#pragma unroll
    for (int j = 0; j < 32; j++) hs[j] = 0.f;
    float sDp = Dp[h];
    long rowbase = (long)b * T;

    const float* gB = xbc + rowbase * CCH + 2048 + 2 * l;
    const float* gC = xbc + rowbase * CCH + 2176 + 2 * l;
    const float* gX = xbc + rowbase * CCH + h * 64 + q * 16 + pl;
    const float* gDt = dtb + rowbase * NH + h;
    const float* gDa = dab + rowbase * NH + h;
    float* yout = ys + rowbase * DIN + h * 64 + q * 16 + pl;

    int wr2 = 2 * l + ((2 * l) >> 5) * 4;        // padded LDS index for this lane's pair

    float2 rB[8], rC[8];
    float rX[8], rDt[8], rDa[8];
    // prologue: fill ring with t = 0..7, stage LDS slots for t = 0,1
#pragma unroll
    for (int k = 0; k < 8; k++) {
        long o = (long)k * CCH;
        rB[k] = *(const float2*)(gB + o);
        rC[k] = *(const float2*)(gC + o);
        rX[k] = gX[o];
        rDt[k] = gDt[(long)k * NH];
        rDa[k] = gDa[(long)k * NH];
    }
#pragma unroll
    for (int k = 0; k < 2; k++) {
        *(float2*)&lB[k][wr2] = rB[k];
        *(float2*)&lC[k][wr2] = rC[k];
    }

    for (int t = 0; t < T; t += 8) {
#pragma unroll
        for (int j = 0; j < 8; j++) {
            int tt = t + j;
            // 1. stage LDS slot for step tt+2 from ring slot (j+2)&7
            if (tt + 2 < T) {
                int js = (j + 2) & 7, ls2 = (tt + 2) & 3;
                *(float2*)&lB[ls2][wr2] = rB[js];
                *(float2*)&lC[ls2][wr2] = rC[js];
            }
            // 2. consume step tt from LDS slot tt&3 + ring regs
            int ls = tt & 3;
            float xt = rX[j];
            float dtx = rDt[j] * xt;
            float dac = rDa[j];
            const float4* bp = (const float4*)&lB[ls][sub * 36];
            const float4* cp = (const float4*)&lC[ls][sub * 36];
            float y0 = 0.f, y1 = 0.f, y2 = 0.f, y3 = 0.f;
#pragma unroll
            for (int g = 0; g < 8; g++) {
                float4 bv = bp[g];
                float4 cv = cp[g];
                hs[g * 4 + 0] = fmaf(dac, hs[g * 4 + 0], dtx * bv.x); y0 = fmaf(hs[g * 4 + 0], cv.x, y0);
                hs[g * 4 + 1] = fmaf(dac, hs[g * 4 + 1], dtx * bv.y); y1 = fmaf(hs[g * 4 + 1], cv.y, y1);
                hs[g * 4 + 2] = fmaf(dac, hs[g * 4 + 2], dtx * bv.z); y2 = fmaf(hs[g * 4 + 2], cv.z, y2);
                hs[g * 4 + 3] = fmaf(dac, hs[g * 4 + 3], dtx * bv.w); y3 = fmaf(hs[g * 4 + 3], cv.w, y3);
            }
            float y = (y0 + y1) + (y2 + y3);
            y += __shfl_xor(y, 1);
            y += __shfl_xor(y, 2);
            if (sub == 0) yout[(long)tt * DIN] = y + sDp * xt;
            // 3. refill ring slot j with step tt+8
            if (tt + 8 < T) {
                long o = (long)(tt + 8) * CCH;
                rB[j] = *(const float2*)(gB + o);
                rC[j] = *(const float2*)(gC + o);
                rX[j] = gX[o];
                rDt[j] = gDt[(long)(tt + 8) * NH];
                rDa[j] = gDa[(long)(tt + 8) * NH];
            }
        }
    }
}

// -------------------------------------------- rmsnorm(y_scan * silu(z)), in-place
__global__ __launch_bounds__(256) void ssmnorm_kernel(float* __restrict__ ys, const float* __restrict__ z,
                                                      const float* __restrict__ w) {
    long row = blockIdx.x; int tid = threadIdx.x;
    float* yr = ys + row * DIN;
    const float* zr = z + row * DIN;
    double v[8]; double ss = 0.0;
#pragma unroll
    for (int j = 0; j < 8; j++) {
        int c = tid * 8 + j;
        double zz = (double)zr[c];
        double val = (double)yr[c] * (zz * sigd(zz));
        v[j] = val; ss += val * val;
    }
    for (int off = 1; off < 64; off <<= 1) ss += __shfl_xor(ss, off);
    __shared__ double tmp[4];
    if ((tid & 63) == 0) tmp[tid >> 6] = ss;
    __syncthreads();
    double tot = tmp[0] + tmp[1] + tmp[2] + tmp[3];
    double scale = 1.0 / sqrt(tot / (double)DIN + 1e-5);
#pragma unroll
    for (int j = 0; j < 8; j++) {
        int c = tid * 8 + j;
        yr[c] = (float)(v[j] * scale * (double)w[c]);
    }
}

// ------------------------------------------------------- score head (2)
__global__ void score2_kernel(const float* __restrict__ sh, const float* __restrict__ w2,
                              float* __restrict__ scores, double* __restrict__ ssum) {
    int row = blockIdx.x * 4 + (threadIdx.x >> 6);
    int lane = threadIdx.x & 63;
    const float* h = sh + (long)row * 256;
    double a = 0.0;
    for (int j = 0; j < 4; j++) a += (double)h[lane * 4 + j] * (double)w2[lane * 4 + j];
    for (int off = 1; off < 64; off <<= 1) a += __shfl_xor(a, off);
    if (lane == 0) {
        double sc = sigd(a);
        scores[row] = (float)sc;
        atomicAdd(&ssum[row >> 11], sc);
    }
}

// ------------------------------------------------ top-64 (stable argsort)
__global__ void top64_kernel(const float* __restrict__ scores, int* __restrict__ tidx, float* __restrict__ tval) {
    int b = blockIdx.x; int tid = threadIdx.x;
    __shared__ float s[T];
    __shared__ float rv[256];
    __shared__ int ri[256];
    for (int i = tid; i < T; i += 256) s[i] = scores[b * T + i];
    for (int k = 0; k < 64; k++) {
        __syncthreads();
        float best = -1e30f; int bi = 1 << 30;
        for (int i = tid; i < T; i += 256) {
            float v = s[i];
            if (v > best || (v == best && i < bi)) { best = v; bi = i; }
        }
        rv[tid] = best; ri[tid] = bi;
        __syncthreads();
        for (int off = 128; off > 0; off >>= 1) {
            if (tid < off) {
                float v2 = rv[tid + off]; int i2 = ri[tid + off];
                if (v2 > rv[tid] || (v2 == rv[tid] && i2 < ri[tid])) { rv[tid] = v2; ri[tid] = i2; }
            }
            __syncthreads();
        }
        if (tid == 0) { tidx[b * 64 + k] = ri[0]; tval[b * 64 + k] = rv[0]; s[ri[0]] = -1e30f; }
    }
}

// ---------------------------------------------------- summaries (64/b)
__global__ __launch_bounds__(256) void summ_kernel(const float* __restrict__ y, const int* __restrict__ tidx,
                                                   const float* __restrict__ wsum, float* __restrict__ summ) {
    int s = blockIdx.x & 63; int b = blockIdx.x >> 6;
    int tid = threadIdx.x;
    __shared__ float yrow[1024];
    int tok = tidx[b * 64 + s];
    long base = ((long)(b * T + tok));
    for (int i = tid; i < 1024; i += 256) yrow[i] = y[base * 1024 + i];
    __syncthreads();
    double acc = 0.0;
    const float* w = wsum + (long)tid * 1024;
    for (int kk = 0; kk < 1024; kk++) acc += (double)yrow[kk] * (double)w[kk];
    summ[((long)(b * 64 + s)) * 256 + tid] = (float)acc;
}

// -------------------------------------------------------- pool update
__global__ void pool_kernel(const float* __restrict__ pin, const float* __restrict__ prin,
                            const int* __restrict__ cin, const float* __restrict__ tval,
                            const float* __restrict__ summ, const double* __restrict__ ssum,
                            float* __restrict__ pout, float* __restrict__ prout,
                            float* __restrict__ cout, float* __restrict__ rmask) {
    int b = blockIdx.x; int tid = threadIdx.x;
    __shared__ float spri[64];
    __shared__ int scount, sact, sslot, srep, srslot;
    for (int i = tid; i < 64 * 256; i += 256) pout[(long)b * 16384 + i] = pin[(long)b * 16384 + i];
    if (tid < 64) spri[tid] = prin[b * 64 + tid];
    if (tid == 0) scount = cin[b];
    __syncthreads();
    for (int s = 0; s < 64; s++) {
        float imp = tval[b * 64 + s];
        bool has = imp > 0.5f;                       // TAU1
        if (tid == 0) {
            sact = 0;
            if (has && scount < 64) { sslot = scount; spri[scount] = imp; scount++; sact = 1; }
        }
        __syncthreads();
        if (sact) pout[((long)(b * 64 + sslot)) * 256 + tid] = summ[((long)(b * 64 + s)) * 256 + tid];
        if (tid < 64) {
            float v = spri[tid]; int idx = tid;
            for (int off = 1; off < 64; off <<= 1) {
                float v2 = __shfl_xor(v, off); int i2 = __shfl_xor(idx, off);
                if (v2 < v || (v2 == v && i2 < idx)) { v = v2; idx = i2; }
            }
            if (tid == 0) {
                srep = 0;
                if (has && scount >= 64 && imp > v) { srep = 1; srslot = idx; spri[idx] = imp; }
            }
        }
        __syncthreads();
        if (srep) pout[((long)(b * 64 + srslot)) * 256 + tid] = summ[((long)(b * 64 + s)) * 256 + tid];
        __syncthreads();
    }
    if (tid < 64) prout[b * 64 + tid] = spri[tid];
    if (tid == 0) {
        cout[b] = (float)scount;
        double mean = ssum[b] / (double)T;
        rmask[b] = (mean > 0.4 && scount > 0) ? 1.f : 0.f;
    }
}

// ------------------------------------------------------------ k,v proj
__global__ __launch_bounds__(256) void kv_kernel(const float* __restrict__ pool, const float* __restrict__ kw,
                                                 const float* __restrict__ vw, float* __restrict__ k,
                                                 float* __restrict__ v) {
    int blk = blockIdx.x; int b = blk >> 6, s = blk & 63; int tid = threadIdx.x;
    __shared__ float pr[256];
    pr[tid] = pool[((long)(b * 64 + s)) * 256 + tid];
    __syncthreads();
    float a = 0.f;
    const float* w = kw + (long)tid * 256;
    for (int j = 0; j < 256; j++) a = fmaf(pr[j], w[j], a);
    k[((long)(b * 64 + s)) * 256 + tid] = a;
    for (int m = 0; m < 4; m++) {
        int o = m * 256 + tid;
        const float* w2 = vw + (long)o * 256;
        float c = 0.f;
        for (int j = 0; j < 256; j++) c = fmaf(pr[j], w2[j], c);
        v[((long)(b * 64 + s)) * 1024 + o] = c;
    }
}

// ----------------------------------------------------- pool attention
__global__ __launch_bounds__(256) void attn_kernel(const float* __restrict__ q, const float* __restrict__ k,
                                                   const float* __restrict__ v, const float* __restrict__ cout,
                                                   float* __restrict__ concat) {
    long row = blockIdx.x;
    int b = (int)(row >> 11);
    int tid = threadIdx.x;
    int cnt = (int)cout[b];
    __shared__ float qs[256], slog[64], sp[64];
    qs[tid] = q[row * 256 + tid];
    __syncthreads();
    int s = tid >> 2, part = tid & 3;
    const float* kr = k + ((long)(b * 64 + s)) * 256 + part * 64;
    float d = 0.f;
    for (int j = 0; j < 64; j++) d = fmaf(qs[part * 64 + j], kr[j], d);
    d += __shfl_xor(d, 1); d += __shfl_xor(d, 2);
    if (part == 0) slog[s] = d * 0.0625f;
    __syncthreads();
    if (tid < 64) {
        float l = (tid < cnt) ? slog[tid] : -1e30f;
        float m = l;
        for (int off = 1; off < 64; off <<= 1) m = fmaxf(m, __shfl_xor(m, off));
        float e = (tid < cnt) ? expf(l - m) : 0.f;
        float su = e;
        for (int off = 1; off < 64; off <<= 1) su += __shfl_xor(su, off);
        sp[tid] = (cnt > 0) ? e / su : 0.f;
    }
    __syncthreads();
    float acc[4] = {0.f, 0.f, 0.f, 0.f};
    for (int s2 = 0; s2 < cnt; s2++) {
        float p = sp[s2];
        const float* vr = v + ((long)(b * 64 + s2)) * 1024 + tid;
        acc[0] = fmaf(p, vr[0], acc[0]);
        acc[1] = fmaf(p, vr[256], acc[1]);
        acc[2] = fmaf(p, vr[512], acc[2]);
        acc[3] = fmaf(p, vr[768], acc[3]);
    }
    for (int j = 0; j < 4; j++) concat[row * 2048 + 1024 + tid + j * 256] = acc[j];
}

// ===========================================================================
extern "C" void kernel_launch(void* const* d_in, const int* in_sizes, int n_in,
                              void* d_out, int out_size, void* d_ws, size_t ws_size,
                              hipStream_t stream) {
    (void)in_sizes; (void)n_in; (void)out_size;
    const float* x       = (const float*)d_in[0];
    const float* pool_in = (const float*)d_in[1];
    const float* pri_in  = (const float*)d_in[2];
    const int*   cnt_in  = (const int*)d_in[3];
    const float* norm_w  = (const float*)d_in[4];
    const float* in_w    = (const float*)d_in[5];
    const float* conv_w  = (const float*)d_in[6];
    const float* conv_b  = (const float*)d_in[7];
    const float* dt_bias = (const float*)d_in[8];
    const float* A_log   = (const float*)d_in[9];
    const float* Dp      = (const float*)d_in[10];
    const float* ssm_w   = (const float*)d_in[11];
    const float* out_w   = (const float*)d_in[12];
    const float* s_w1    = (const float*)d_in[13];
    const float* s_w2    = (const float*)d_in[14];
    const float* summ_w  = (const float*)d_in[15];
    const float* q_w     = (const float*)d_in[16];
    const float* k_w     = (const float*)d_in[17];
    const float* v_w     = (const float*)d_in[18];
    const float* gate_w  = (const float*)d_in[19];

    float* outy    = (float*)d_out;
    float* outpool = outy + (long)ROWS * D;
    float* outpri  = outpool + Bb * 64 * 256;
    float* outcnt  = outpri + Bb * 64;

    char* ws = (char*)d_ws;
    size_t cur = 0;
    auto alloc = [&](size_t bytes) { size_t o = cur; cur += (bytes + 255) / 256 * 256; return o; };

    size_t o_dt   = alloc((size_t)ROWS * NH * 4);
    size_t o_da   = alloc((size_t)ROWS * NH * 4);
    size_t o_sc   = alloc((size_t)ROWS * 4);
    size_t o_ssum = alloc(64);
    size_t o_rmk  = alloc(64);
    size_t o_tidx = alloc(Bb * 64 * 4);
    size_t o_tval = alloc(Bb * 64 * 4);
    size_t o_summ = alloc((size_t)Bb * 64 * 256 * 4);
    size_t o_k    = alloc((size_t)Bb * 64 * 256 * 4);
    size_t o_v    = alloc((size_t)Bb * 64 * 1024 * 4);
    size_t o_RA = alloc((size_t)ROWS * CCH * 4);   // xbc -> concat+sch
    size_t o_RB = alloc((size_t)ROWS * DIN * 4);   // bufZ -> qbuf
    size_t o_RC = alloc((size_t)ROWS * CCH * 4);   // bufX -> yscan/normed (in-place)

    if (ws_size < cur) {   // diagnostic: report ws_size in MB via absmax
        diag_kernel<<<1, 64, 0, stream>>>(outy, 1000.0f + (float)(ws_size >> 20));
        return;
    }

    float* dtb    = (float*)(ws + o_dt);
    float* dab    = (float*)(ws + o_da);
    float* scores = (float*)(ws + o_sc);
    double* ssum  = (double*)(ws + o_ssum);
    float* rmk    = (float*)(ws + o_rmk);
    int*   tidx   = (int*)(ws + o_tidx);
    float* tval   = (float*)(ws + o_tval);
    float* summ   = (float*)(ws + o_summ);
    float* kbuf   = (float*)(ws + o_k);
    float* vbuf   = (float*)(ws + o_v);

    float* xbc    = (float*)(ws + o_RA);
    float* concat = (float*)(ws + o_RA);
    float* sch    = (float*)(ws + o_RA + (size_t)ROWS * DIN * 4);
    float* bufZ   = (float*)(ws + o_RB);
    float* qbuf   = (float*)(ws + o_RB);
    float* bufX   = (float*)(ws + o_RC);
    float* yscan  = (float*)(ws + o_RC);

    // 0. init
    zerod_kernel<<<1, 64, 0, stream>>>(ssum, 4);
    // 1. rmsnorm(x) -> u (stored in outy region of d_out)
    rms_x_kernel<<<ROWS, 256, 0, stream>>>(x, norm_w, outy);
    // 2. in_proj (6-term split): -> bufZ (z), bufX (xBC), dt/dA (f32)
    gemm_f32<3, 0><<<dim3(35, 64), 256, 0, stream>>>(outy, 1024, in_w, 1024, ROWS, DPROJ, 1024,
                                                     bufZ, bufX, dt_bias, A_log, dtb, dab);
    // 3. conv + silu (f64 math) -> xbc (R_A)
    conv_kernel<<<Bb * 32 * 36, 256, 0, stream>>>(bufX, conv_w, conv_b, xbc);
    // 4. scan (8-deep pipelined register scan) -> yscan (R_C, over dead bufX)
    scan_kernel<<<Bb * NH * 4, 64, 0, stream>>>(xbc, dtb, dab, Dp, yscan);
    // 5. ssm rmsnorm (f64, in-place over yscan)
    ssmnorm_kernel<<<ROWS, 256, 0, stream>>>(yscan, bufZ, ssm_w);
    // 6. out_proj (6-term split) + residual -> outy, concat (R_A, over dead xbc)
    gemm_f32<3, 2><<<dim3(8, 64), 256, 0, stream>>>(yscan, 2048, out_w, 2048, ROWS, 1024, 2048,
                                                    outy, concat, x, nullptr, nullptr, nullptr);
    // 7. score1 (6-term split, relu) -> sch
    gemm_f32<3, 1><<<dim3(2, 64), 256, 0, stream>>>(outy, 1024, s_w1, 1024, ROWS, 256, 1024,
                                                    sch, nullptr, nullptr, nullptr, nullptr, nullptr);
    // 8. score2 (f64) -> scores, ssum
    score2_kernel<<<ROWS / 4, 256, 0, stream>>>(sch, s_w2, scores, ssum);
    // 9. top-64
    top64_kernel<<<Bb, 256, 0, stream>>>(scores, tidx, tval);
    // 10. summaries (f32 y, f64 accum)
    summ_kernel<<<Bb * 64, 256, 0, stream>>>(outy, tidx, summ_w, summ);
    // 11. pool update -> d_out pool/pri/counts + rmask
    pool_kernel<<<Bb, 256, 0, stream>>>(pool_in, pri_in, cnt_in, tval, summ, ssum,
                                        outpool, outpri, outcnt, rmk);
    // 12. k, v
    kv_kernel<<<Bb * 64, 256, 0, stream>>>(outpool, k_w, v_w, kbuf, vbuf);
    // 13. q = y @ q_w^T (plain bf16)
    gemm_f32<1, 3><<<dim3(2, 64), 256, 0, stream>>>(outy, 1024, q_w, 1024, ROWS, 256, 1024,
                                                    qbuf, nullptr, nullptr, nullptr, nullptr, nullptr);
    // 14. attention -> retrieved (f32, concat second half)
    attn_kernel<<<ROWS, 256, 0, stream>>>(qbuf, kbuf, vbuf, outcnt, concat);
    // 15. gate GEMM (plain bf16) + final y update
    gemm_f32<1, 4><<<dim3(8, 64), 256, 0, stream>>>(concat, 2048, gate_w, 2048, ROWS, 1024, 2048,
                                                    outy, nullptr, concat, rmk, nullptr, nullptr);
}

// Round 5
// 2708.709 us; speedup vs baseline: 1.1267x; 1.0114x over previous
//
#include <hip/hip_runtime.h>

// ---------------------------------------------------------------------------
// MemMambaBlock on MI355X.  B=4 T=2048 D=1024 D_INNER=2048 D_STATE=128
// NHEADS=32 HEADDIM=64 D_CONV=4 POOL=64 SUMDIM=256 d_in_proj=4384
// Precision: 6-term 3-way-bf16-split MFMA (~f32-exact) for in_proj/out_proj/
// score1 (score ORDERING is discrete); f64 for conv/norms/score head;
// f32 register-resident wave-synchronous sequential scan (matches reference
// f32 recurrence associativity); plain bf16 MFMA for q/gate (smooth paths).
// Scan v4: v3 + __launch_bounds__(64,1) so the allocator keeps the 8-deep
// register rings live (R4 showed the occupancy heuristic de-pipelined them).
// GEMM v2: weights pre-split into 3 bf16 planes once (B-side staging becomes
// a u16 copy); planes live in dead workspace regions (no footprint growth).
// ---------------------------------------------------------------------------

using u16 = unsigned short;
using bf16x8 = __attribute__((ext_vector_type(8))) short;
using f32x4  = __attribute__((ext_vector_type(4))) float;

#define DEV __device__ __forceinline__

static constexpr int Bb = 4, T = 2048, D = 1024;
static constexpr int DIN = 2048, DST = 128, NH = 32;
static constexpr int DPROJ = 4384;          // 2*DIN + 2*DST + NH
static constexpr int CCH = 2304;            // DIN + 2*DST (conv channels)
static constexpr int ROWS = Bb * T;         // 8192

DEV float bf2f(u16 h) { union { unsigned int u; float f; } v; v.u = ((unsigned int)h) << 16; return v.f; }
DEV u16 f2bf(float f) { union { float f; unsigned int u; } v; v.f = f; unsigned int r = v.u + 0x7fffu + ((v.u >> 16) & 1u); return (u16)(r >> 16); }
DEV double sigd(double x) { return 1.0 / (1.0 + exp(-x)); }

__global__ void diag_kernel(float* o, float v) { if (threadIdx.x == 0) o[0] = v; }
__global__ void zerod_kernel(double* p, int n) { if ((int)threadIdx.x < n) p[threadIdx.x] = 0.0; }

// --------------------------------------------- 3-plane bf16 weight split
__global__ void split3_kernel(const float* __restrict__ in, u16* __restrict__ out, long n) {
    long i = (long)blockIdx.x * 256 + threadIdx.x;
    if (i >= n) return;
    float v = in[i];
    u16 h = f2bf(v);
    float r1 = v - bf2f(h);
    u16 m = f2bf(r1);
    out[i] = h;
    out[n + i] = m;
    out[2 * n + i] = f2bf(r1 - bf2f(m));
}

// ------------------------------------------------------------- rmsnorm(x)
__global__ __launch_bounds__(256) void rms_x_kernel(const float* __restrict__ x, const float* __restrict__ w,
                                                    float* __restrict__ u) {
    long row = blockIdx.x; int tid = threadIdx.x;
    const float* xr = x + row * D;
    float4 xv = *(const float4*)(xr + tid * 4);
    double ss = (double)xv.x * xv.x + (double)xv.y * xv.y + (double)xv.z * xv.z + (double)xv.w * xv.w;
    for (int off = 1; off < 64; off <<= 1) ss += __shfl_xor(ss, off);
    __shared__ double tmp[4];
    if ((tid & 63) == 0) tmp[tid >> 6] = ss;
    __syncthreads();
    double tot = tmp[0] + tmp[1] + tmp[2] + tmp[3];
    double scale = 1.0 / sqrt(tot / (double)D + 1e-4);
    float4 wv = *(const float4*)(w + tid * 4);
    long base = row * D + tid * 4;
    u[base + 0] = (float)((double)xv.x * scale * (double)wv.x);
    u[base + 1] = (float)((double)xv.y * scale * (double)wv.y);
    u[base + 2] = (float)((double)xv.z * scale * (double)wv.z);
    u[base + 3] = (float)((double)xv.w * scale * (double)wv.w);
}

// ----------------------------------------------------------------- GEMM
// C[M][N] = A[M][K] @ Bt[N][K]^T.  A: f32 source, on-the-fly bf16 split
// (NP planes).  B: if BP, pre-split u16 planes (stride bstride); else f32.
// MODE 0: in_proj epilogue   MODE 1: relu->sch   MODE 2: y=x+C->outy+concat
// MODE 3: ->qbuf             MODE 4: outy += sigmoid(C)*retr*rmask
template <int NP>
DEV void stage_one(u16* s0, u16* s1, u16* s2, const float* __restrict__ src, long ld,
                   int row0, int lastrow, int k0, int tid) {
    int r = tid >> 1, c0 = (tid & 1) << 4;
    long rg = row0 + r; if (rg > lastrow) rg = lastrow;
    const float* p = src + rg * ld + k0 + c0;
    int base = r * 32 + c0;
#pragma unroll
    for (int q = 0; q < 4; q++) {
        float4 v4 = *(const float4*)(p + q * 4);
        float vv[4] = { v4.x, v4.y, v4.z, v4.w };
#pragma unroll
        for (int j = 0; j < 4; j++) {
            float xv = vv[j];
            u16 h = f2bf(xv);
            s0[base + q * 4 + j] = h;
            if constexpr (NP == 3) {
                float r1 = xv - bf2f(h);
                u16 m = f2bf(r1);
                s1[base + q * 4 + j] = m;
                float r2 = r1 - bf2f(m);
                s2[base + q * 4 + j] = f2bf(r2);
            }
        }
    }
}

DEV void stage_pre(u16* dst, const u16* __restrict__ src, long ld, int row0, int lastrow, int k0, int tid) {
    int r = tid >> 1, c = (tid & 1) << 4;
    long rg = row0 + r; if (rg > lastrow) rg = lastrow;
    const u16* p = src + rg * ld + k0 + c;
    *(uint4*)(dst + r * 32 + c)     = *(const uint4*)p;
    *(uint4*)(dst + r * 32 + c + 8) = *(const uint4*)(p + 8);
}

template <int NP, int MODE, bool BP>
__global__ __launch_bounds__(256) void gemm_f32(
    const float* __restrict__ A, long lda,
    const float* __restrict__ B, long ldb,
    const u16* __restrict__ Bp, size_t bstride,
    int M, int N, int K,
    float* __restrict__ out0, float* __restrict__ out1,
    const float* __restrict__ aux0, const float* __restrict__ aux1,
    float* __restrict__ dtb, float* __restrict__ dab) {
    __shared__ __align__(16) u16 sm[NP * 2 * 4096];
    u16* As[3]; u16* Bs[3];
#pragma unroll
    for (int p = 0; p < NP; p++) { As[p] = sm + p * 4096; Bs[p] = sm + (NP + p) * 4096; }
    int tid = threadIdx.x, lane = tid & 63, wid = tid >> 6;
    int wr = wid >> 1, wc = wid & 1;
    int tM = blockIdx.y * 128, tN = blockIdx.x * 128;

    f32x4 acc[4][4];
#pragma unroll
    for (int i = 0; i < 4; i++)
#pragma unroll
        for (int j = 0; j < 4; j++) acc[i][j] = f32x4{0.f, 0.f, 0.f, 0.f};

    int nsteps = K / 32;
    for (int kt = 0; kt < nsteps; ++kt) {
        int k0 = kt * 32;
        __syncthreads();
        stage_one<NP>(As[0], NP == 3 ? As[1] : nullptr, NP == 3 ? As[2] : nullptr, A, lda, tM, M - 1, k0, tid);
        if constexpr (BP) {
#pragma unroll
            for (int p = 0; p < NP; p++)
                stage_pre(Bs[p], Bp + (size_t)p * bstride, K, tN, N - 1, k0, tid);
        } else {
            stage_one<NP>(Bs[0], NP == 3 ? Bs[1] : nullptr, NP == 3 ? Bs[2] : nullptr, B, ldb, tN, N - 1, k0, tid);
        }
        __syncthreads();
        int rA = wr * 64 + (lane & 15);
        int rB = wc * 64 + (lane & 15);
        int kk = (lane >> 4) * 8;
        bf16x8 af[NP][4], bfr[NP][4];
#pragma unroll
        for (int p = 0; p < NP; p++)
#pragma unroll
            for (int i = 0; i < 4; i++) {
                af[p][i]  = *(const bf16x8*)(As[p] + (rA + i * 16) * 32 + kk);
                bfr[p][i] = *(const bf16x8*)(Bs[p] + (rB + i * 16) * 32 + kk);
            }
#pragma unroll
        for (int mi = 0; mi < 4; mi++)
#pragma unroll
            for (int ni = 0; ni < 4; ni++) {
                acc[mi][ni] = __builtin_amdgcn_mfma_f32_16x16x32_bf16(af[0][mi], bfr[0][ni], acc[mi][ni], 0, 0, 0);
                if constexpr (NP == 3) {
                    acc[mi][ni] = __builtin_amdgcn_mfma_f32_16x16x32_bf16(af[0][mi], bfr[1][ni], acc[mi][ni], 0, 0, 0);
                    acc[mi][ni] = __builtin_amdgcn_mfma_f32_16x16x32_bf16(af[1][mi], bfr[0][ni], acc[mi][ni], 0, 0, 0);
                    acc[mi][ni] = __builtin_amdgcn_mfma_f32_16x16x32_bf16(af[0][mi], bfr[2][ni], acc[mi][ni], 0, 0, 0);
                    acc[mi][ni] = __builtin_amdgcn_mfma_f32_16x16x32_bf16(af[1][mi], bfr[1][ni], acc[mi][ni], 0, 0, 0);
                    acc[mi][ni] = __builtin_amdgcn_mfma_f32_16x16x32_bf16(af[2][mi], bfr[0][ni], acc[mi][ni], 0, 0, 0);
                }
            }
    }
    int laneh = lane >> 4, lanel = lane & 15;
#pragma unroll
    for (int mi = 0; mi < 4; mi++)
#pragma unroll
        for (int ni = 0; ni < 4; ni++) {
            int col = tN + wc * 64 + ni * 16 + lanel;
            if (col >= N) continue;
#pragma unroll
            for (int r = 0; r < 4; r++) {
                long row = tM + wr * 64 + mi * 16 + laneh * 4 + r;
                float v = acc[mi][ni][r];
                if constexpr (MODE == 0) {
                    if (col < 2048) out0[row * 2048 + col] = v;
                    else if (col < 4352) out1[row * 2304 + (col - 2048)] = v;
                    else {
                        int h = col - 4352;
                        double xx = (double)v + (double)aux0[h];
                        double sp = (xx > 30.0) ? xx : log1p(exp(xx));
                        double a = -exp((double)aux1[h]);
                        dtb[row * NH + h] = (float)sp;
                        dab[row * NH + h] = (float)exp(sp * a);
                    }
                } else if constexpr (MODE == 1) {
                    out0[row * 256 + col] = fmaxf(v, 0.f);
                } else if constexpr (MODE == 2) {
                    float y = aux0[row * 1024 + col] + v;
                    out0[row * 1024 + col] = y;
                    out1[row * 2048 + col] = y;
                } else if constexpr (MODE == 3) {
                    out0[row * 256 + col] = v;
                } else {
                    double g = sigd((double)v);
                    float retr = aux0[row * 2048 + 1024 + col];
                    out0[row * 1024 + col] += (float)(g * (double)retr * (double)aux1[row >> 11]);
                }
            }
        }
}

// ------------------------------------------------- depthwise causal conv4
__global__ __launch_bounds__(256) void conv_kernel(const float* __restrict__ xin, const float* __restrict__ cw,
                                                   const float* __restrict__ cb, float* __restrict__ xbc) {
    int blk = blockIdx.x;
    int ct = blk % 36; int tt = (blk / 36) % 32; int b = blk / (36 * 32);
    int c0 = ct * 64, t0 = tt * 64;
    int tid = threadIdx.x;
    __shared__ float tile[67 * 64];
    for (int i = tid; i < 67 * 64; i += 256) {
        int r = i >> 6, c = i & 63;
        int t = t0 - 3 + r;
        tile[i] = (t >= 0) ? xin[((long)(b * T + t)) * CCH + c0 + c] : 0.f;
    }
    __syncthreads();
    int c = tid & 63; int rb = (tid >> 6) * 16;
    int gc = c0 + c;
    double w0 = cw[gc * 4], w1 = cw[gc * 4 + 1], w2 = cw[gc * 4 + 2], w3 = cw[gc * 4 + 3];
    double bias = cb[gc];
    for (int j = 0; j < 16; j++) {
        int tl = rb + j;
        double a = bias + w0 * (double)tile[tl * 64 + c] + w1 * (double)tile[(tl + 1) * 64 + c]
                        + w2 * (double)tile[(tl + 2) * 64 + c] + w3 * (double)tile[(tl + 3) * 64 + c];
        xbc[((long)(b * T + t0 + tl)) * CCH + gc] = (float)(a * sigd(a));
    }
}

// ------------------------------------------------------------- SSM scan v4
// Wave-synchronous register scan, 8-deep software pipeline.
// __launch_bounds__(64, 1): 1 wave/EU min => allocator may use up to ~512
// VGPRs, so the 8-deep rings stay in registers and loads stay hoisted
// (R4: default occupancy heuristic sank the loads => serial latency).
__global__ __launch_bounds__(64, 1) void scan_kernel(const float* __restrict__ xbc, const float* __restrict__ dtb,
                                                     const float* __restrict__ dab, const float* __restrict__ Dp,
                                                     float* __restrict__ ys) {
    int bx = blockIdx.x;
    int b = bx >> 7, h = (bx >> 2) & 31, q = bx & 3;
    int l = threadIdx.x;
    int pl = l >> 2, sub = l & 3;
    __shared__ __align__(16) float lB[4][144];   // 4 groups of (32 data + 4 pad)
    __shared__ __align__(16) float lC[4][144];

    float hs[32];
#pragma unroll
    for (int j = 0; j < 32; j++) hs[j] = 0.f;
    float sDp = Dp[h];
    long rowbase = (long)b * T;

    const float* gB = xbc + rowbase * CCH + 2048 + 2 * l;
    const float* gC = xbc + rowbase * CCH + 2176 + 2 * l;
    const float* gX = xbc + rowbase * CCH + h * 64 + q * 16 + pl;
    const float* gDt = dtb + rowbase * NH + h;
    const float* gDa = dab + rowbase * NH + h;
    float* yout = ys + rowbase * DIN + h * 64 + q * 16 + pl;

    int wr2 = 2 * l + ((2 * l) >> 5) * 4;        // padded LDS index for this lane's pair

    float2 rB[8], rC[8];
    float rX[8], rDt[8], rDa[8];
    // prologue: fill ring with t = 0..7, stage LDS slots for t = 0,1
#pragma unroll
    for (int k = 0; k < 8; k++) {
        long o = (long)k * CCH;
        rB[k] = *(const float2*)(gB + o);
        rC[k] = *(const float2*)(gC + o);
        rX[k] = gX[o];
        rDt[k] = gDt[(long)k * NH];
        rDa[k] = gDa[(long)k * NH];
    }
#pragma unroll
    for (int k = 0; k < 2; k++) {
        *(float2*)&lB[k][wr2] = rB[k];
        *(float2*)&lC[k][wr2] = rC[k];
    }

    for (int t = 0; t < T; t += 8) {
#pragma unroll
        for (int j = 0; j < 8; j++) {
            int tt = t + j;
            // 1. stage LDS slot for step tt+2 from ring slot (j+2)&7
            if (tt + 2 < T) {
                int js = (j + 2) & 7, ls2 = (tt + 2) & 3;
                *(float2*)&lB[ls2][wr2] = rB[js];
                *(float2*)&lC[ls2][wr2] = rC[js];
            }
            // 2. consume step tt from LDS slot tt&3 + ring regs
            int ls = tt & 3;
            float xt = rX[j];
            float dtx = rDt[j] * xt;
            float dac = rDa[j];
            const float4* bp = (const float4*)&lB[ls][sub * 36];
            const float4* cp = (const float4*)&lC[ls][sub * 36];
            float y0 = 0.f, y1 = 0.f, y2 = 0.f, y3 = 0.f;
#pragma unroll
            for (int g = 0; g < 8; g++) {
                float4 bv = bp[g];
                float4 cv = cp[g];
                hs[g * 4 + 0] = fmaf(dac, hs[g * 4 + 0], dtx * bv.x); y0 = fmaf(hs[g * 4 + 0], cv.x, y0);
                hs[g * 4 + 1] = fmaf(dac, hs[g * 4 + 1], dtx * bv.y); y1 = fmaf(hs[g * 4 + 1], cv.y, y1);
                hs[g * 4 + 2] = fmaf(dac, hs[g * 4 + 2], dtx * bv.z); y2 = fmaf(hs[g * 4 + 2], cv.z, y2);
                hs[g * 4 + 3] = fmaf(dac, hs[g * 4 + 3], dtx * bv.w); y3 = fmaf(hs[g * 4 + 3], cv.w, y3);
            }
            float y = (y0 + y1) + (y2 + y3);
            y += __shfl_xor(y, 1);
            y += __shfl_xor(y, 2);
            if (sub == 0) yout[(long)tt * DIN] = y + sDp * xt;
            // 3. refill ring slot j with step tt+8
            if (tt + 8 < T) {
                long o = (long)(tt + 8) * CCH;
                rB[j] = *(const float2*)(gB + o);
                rC[j] = *(const float2*)(gC + o);
                rX[j] = gX[o];
                rDt[j] = gDt[(long)(tt + 8) * NH];
                rDa[j] = gDa[(long)(tt + 8) * NH];
            }
        }
    }
}

// -------------------------------------------- rmsnorm(y_scan * silu(z)), in-place
__global__ __launch_bounds__(256) void ssmnorm_kernel(float* __restrict__ ys, const float* __restrict__ z,
                                                      const float* __restrict__ w) {
    long row = blockIdx.x; int tid = threadIdx.x;
    float* yr = ys + row * DIN;
    const float* zr = z + row * DIN;
    double v[8]; double ss = 0.0;
#pragma unroll
    for (int j = 0; j < 8; j++) {
        int c = tid * 8 + j;
        double zz = (double)zr[c];
        double val = (double)yr[c] * (zz * sigd(zz));
        v[j] = val; ss += val * val;
    }
    for (int off = 1; off < 64; off <<= 1) ss += __shfl_xor(ss, off);
    __shared__ double tmp[4];
    if ((tid & 63) == 0) tmp[tid >> 6] = ss;
    __syncthreads();
    double tot = tmp[0] + tmp[1] + tmp[2] + tmp[3];
    double scale = 1.0 / sqrt(tot / (double)DIN + 1e-5);
#pragma unroll
    for (int j = 0; j < 8; j++) {
        int c = tid * 8 + j;
        yr[c] = (float)(v[j] * scale * (double)w[c]);
    }
}

// ------------------------------------------------------- score head (2)
__global__ void score2_kernel(const float* __restrict__ sh, const float* __restrict__ w2,
                              float* __restrict__ scores, double* __restrict__ ssum) {
    int row = blockIdx.x * 4 + (threadIdx.x >> 6);
    int lane = threadIdx.x & 63;
    const float* h = sh + (long)row * 256;
    double a = 0.0;
    for (int j = 0; j < 4; j++) a += (double)h[lane * 4 + j] * (double)w2[lane * 4 + j];
    for (int off = 1; off < 64; off <<= 1) a += __shfl_xor(a, off);
    if (lane == 0) {
        double sc = sigd(a);
        scores[row] = (float)sc;
        atomicAdd(&ssum[row >> 11], sc);
    }
}

// ------------------------------------------------ top-64 (stable argsort)
__global__ void top64_kernel(const float* __restrict__ scores, int* __restrict__ tidx, float* __restrict__ tval) {
    int b = blockIdx.x; int tid = threadIdx.x;
    __shared__ float s[T];
    __shared__ float rv[256];
    __shared__ int ri[256];
    for (int i = tid; i < T; i += 256) s[i] = scores[b * T + i];
    for (int k = 0; k < 64; k++) {
        __syncthreads();
        float best = -1e30f; int bi = 1 << 30;
        for (int i = tid; i < T; i += 256) {
            float v = s[i];
            if (v > best || (v == best && i < bi)) { best = v; bi = i; }
        }
        rv[tid] = best; ri[tid] = bi;
        __syncthreads();
        for (int off = 128; off > 0; off >>= 1) {
            if (tid < off) {
                float v2 = rv[tid + off]; int i2 = ri[tid + off];
                if (v2 > rv[tid] || (v2 == rv[tid] && i2 < ri[tid])) { rv[tid] = v2; ri[tid] = i2; }
            }
            __syncthreads();
        }
        if (tid == 0) { tidx[b * 64 + k] = ri[0]; tval[b * 64 + k] = rv[0]; s[ri[0]] = -1e30f; }
    }
}

// ---------------------------------------------------- summaries (64/b)
__global__ __launch_bounds__(256) void summ_kernel(const float* __restrict__ y, const int* __restrict__ tidx,
                                                   const float* __restrict__ wsum, float* __restrict__ summ) {
    int s = blockIdx.x & 63; int b = blockIdx.x >> 6;
    int tid = threadIdx.x;
    __shared__ float yrow[1024];
    int tok = tidx[b * 64 + s];
    long base = ((long)(b * T + tok));
    for (int i = tid; i < 1024; i += 256) yrow[i] = y[base * 1024 + i];
    __syncthreads();
    double acc = 0.0;
    const float* w = wsum + (long)tid * 1024;
    for (int kk = 0; kk < 1024; kk++) acc += (double)yrow[kk] * (double)w[kk];
    summ[((long)(b * 64 + s)) * 256 + tid] = (float)acc;
}

// -------------------------------------------------------- pool update
__global__ void pool_kernel(const float* __restrict__ pin, const float* __restrict__ prin,
                            const int* __restrict__ cin, const float* __restrict__ tval,
                            const float* __restrict__ summ, const double* __restrict__ ssum,
                            float* __restrict__ pout, float* __restrict__ prout,
                            float* __restrict__ cout, float* __restrict__ rmask) {
    int b = blockIdx.x; int tid = threadIdx.x;
    __shared__ float spri[64];
    __shared__ int scount, sact, sslot, srep, srslot;
    for (int i = tid; i < 64 * 256; i += 256) pout[(long)b * 16384 + i] = pin[(long)b * 16384 + i];
    if (tid < 64) spri[tid] = prin[b * 64 + tid];
    if (tid == 0) scount = cin[b];
    __syncthreads();
    for (int s = 0; s < 64; s++) {
        float imp = tval[b * 64 + s];
        bool has = imp > 0.5f;                       // TAU1
        if (tid == 0) {
            sact = 0;
            if (has && scount < 64) { sslot = scount; spri[scount] = imp; scount++; sact = 1; }
        }
        __syncthreads();
        if (sact) pout[((long)(b * 64 + sslot)) * 256 + tid] = summ[((long)(b * 64 + s)) * 256 + tid];
        if (tid < 64) {
            float v = spri[tid]; int idx = tid;
            for (int off = 1; off < 64; off <<= 1) {
                float v2 = __shfl_xor(v, off); int i2 = __shfl_xor(idx, off);
                if (v2 < v || (v2 == v && i2 < idx)) { v = v2; idx = i2; }
            }
            if (tid == 0) {
                srep = 0;
                if (has && scount >= 64 && imp > v) { srep = 1; srslot = idx; spri[idx] = imp; }
            }
        }
        __syncthreads();
        if (srep) pout[((long)(b * 64 + srslot)) * 256 + tid] = summ[((long)(b * 64 + s)) * 256 + tid];
        __syncthreads();
    }
    if (tid < 64) prout[b * 64 + tid] = spri[tid];
    if (tid == 0) {
        cout[b] = (float)scount;
        double mean = ssum[b] / (double)T;
        rmask[b] = (mean > 0.4 && scount > 0) ? 1.f : 0.f;
    }
}

// ------------------------------------------------------------ k,v proj
__global__ __launch_bounds__(256) void kv_kernel(const float* __restrict__ pool, const float* __restrict__ kw,
                                                 const float* __restrict__ vw, float* __restrict__ k,
                                                 float* __restrict__ v) {
    int blk = blockIdx.x; int b = blk >> 6, s = blk & 63; int tid = threadIdx.x;
    __shared__ float pr[256];
    pr[tid] = pool[((long)(b * 64 + s)) * 256 + tid];
    __syncthreads();
    float a = 0.f;
    const float* w = kw + (long)tid * 256;
    for (int j = 0; j < 256; j++) a = fmaf(pr[j], w[j], a);
    k[((long)(b * 64 + s)) * 256 + tid] = a;
    for (int m = 0; m < 4; m++) {
        int o = m * 256 + tid;
        const float* w2 = vw + (long)o * 256;
        float c = 0.f;
        for (int j = 0; j < 256; j++) c = fmaf(pr[j], w2[j], c);
        v[((long)(b * 64 + s)) * 1024 + o] = c;
    }
}

// ----------------------------------------------------- pool attention
__global__ __launch_bounds__(256) void attn_kernel(const float* __restrict__ q, const float* __restrict__ k,
                                                   const float* __restrict__ v, const float* __restrict__ cout,
                                                   float* __restrict__ concat) {
    long row = blockIdx.x;
    int b = (int)(row >> 11);
    int tid = threadIdx.x;
    int cnt = (int)cout[b];
    __shared__ float qs[256], slog[64], sp[64];
    qs[tid] = q[row * 256 + tid];
    __syncthreads();
    int s = tid >> 2, part = tid & 3;
    const float* kr = k + ((long)(b * 64 + s)) * 256 + part * 64;
    float d = 0.f;
    for (int j = 0; j < 64; j++) d = fmaf(qs[part * 64 + j], kr[j], d);
    d += __shfl_xor(d, 1); d += __shfl_xor(d, 2);
    if (part == 0) slog[s] = d * 0.0625f;
    __syncthreads();
    if (tid < 64) {
        float l = (tid < cnt) ? slog[tid] : -1e30f;
        float m = l;
        for (int off = 1; off < 64; off <<= 1) m = fmaxf(m, __shfl_xor(m, off));
        float e = (tid < cnt) ? expf(l - m) : 0.f;
        float su = e;
        for (int off = 1; off < 64; off <<= 1) su += __shfl_xor(su, off);
        sp[tid] = (cnt > 0) ? e / su : 0.f;
    }
    __syncthreads();
    float acc[4] = {0.f, 0.f, 0.f, 0.f};
    for (int s2 = 0; s2 < cnt; s2++) {
        float p = sp[s2];
        const float* vr = v + ((long)(b * 64 + s2)) * 1024 + tid;
        acc[0] = fmaf(p, vr[0], acc[0]);
        acc[1] = fmaf(p, vr[256], acc[1]);
        acc[2] = fmaf(p, vr[512], acc[2]);
        acc[3] = fmaf(p, vr[768], acc[3]);
    }
    for (int j = 0; j < 4; j++) concat[row * 2048 + 1024 + tid + j * 256] = acc[j];
}

// ===========================================================================
extern "C" void kernel_launch(void* const* d_in, const int* in_sizes, int n_in,
                              void* d_out, int out_size, void* d_ws, size_t ws_size,
                              hipStream_t stream) {
    (void)in_sizes; (void)n_in; (void)out_size;
    const float* x       = (const float*)d_in[0];
    const float* pool_in = (const float*)d_in[1];
    const float* pri_in  = (const float*)d_in[2];
    const int*   cnt_in  = (const int*)d_in[3];
    const float* norm_w  = (const float*)d_in[4];
    const float* in_w    = (const float*)d_in[5];
    const float* conv_w  = (const float*)d_in[6];
    const float* conv_b  = (const float*)d_in[7];
    const float* dt_bias = (const float*)d_in[8];
    const float* A_log   = (const float*)d_in[9];
    const float* Dp      = (const float*)d_in[10];
    const float* ssm_w   = (const float*)d_in[11];
    const float* out_w   = (const float*)d_in[12];
    const float* s_w1    = (const float*)d_in[13];
    const float* s_w2    = (const float*)d_in[14];
    const float* summ_w  = (const float*)d_in[15];
    const float* q_w     = (const float*)d_in[16];
    const float* k_w     = (const float*)d_in[17];
    const float* v_w     = (const float*)d_in[18];
    const float* gate_w  = (const float*)d_in[19];

    float* outy    = (float*)d_out;
    float* outpool = outy + (long)ROWS * D;
    float* outpri  = outpool + Bb * 64 * 256;
    float* outcnt  = outpri + Bb * 64;

    char* ws = (char*)d_ws;
    size_t cur = 0;
    auto alloc = [&](size_t bytes) { size_t o = cur; cur += (bytes + 255) / 256 * 256; return o; };

    size_t o_dt   = alloc((size_t)ROWS * NH * 4);
    size_t o_da   = alloc((size_t)ROWS * NH * 4);
    size_t o_sc   = alloc((size_t)ROWS * 4);
    size_t o_ssum = alloc(64);
    size_t o_rmk  = alloc(64);
    size_t o_tidx = alloc(Bb * 64 * 4);
    size_t o_tval = alloc(Bb * 64 * 4);
    size_t o_summ = alloc((size_t)Bb * 64 * 256 * 4);
    size_t o_k    = alloc((size_t)Bb * 64 * 256 * 4);
    size_t o_v    = alloc((size_t)Bb * 64 * 1024 * 4);
    size_t o_RA = alloc((size_t)ROWS * CCH * 4);   // in_w planes -> xbc -> concat+sch
    size_t o_RB = alloc((size_t)ROWS * DIN * 4);   // bufZ -> out_w/s_w1 planes -> qbuf
    size_t o_RC = alloc((size_t)ROWS * CCH * 4);   // bufX -> yscan/normed (in-place)

    if (ws_size < cur) {   // diagnostic: report ws_size in MB via absmax
        diag_kernel<<<1, 64, 0, stream>>>(outy, 1000.0f + (float)(ws_size >> 20));
        return;
    }

    float* dtb    = (float*)(ws + o_dt);
    float* dab    = (float*)(ws + o_da);
    float* scores = (float*)(ws + o_sc);
    double* ssum  = (double*)(ws + o_ssum);
    float* rmk    = (float*)(ws + o_rmk);
    int*   tidx   = (int*)(ws + o_tidx);
    float* tval   = (float*)(ws + o_tval);
    float* summ   = (float*)(ws + o_summ);
    float* kbuf   = (float*)(ws + o_k);
    float* vbuf   = (float*)(ws + o_v);

    // region A: in_w planes (dead before conv) -> xbc -> concat + sch
    u16*  pw_in   = (u16*)(ws + o_RA);                     // 3 x 4384 x 1024 u16 = 26.9 MB
    float* xbc    = (float*)(ws + o_RA);
    float* concat = (float*)(ws + o_RA);
    float* sch    = (float*)(ws + o_RA + (size_t)ROWS * DIN * 4);
    // region B: bufZ -> {out_w planes, s_w1 planes} -> qbuf
    float* bufZ   = (float*)(ws + o_RB);
    u16*  pw_out  = (u16*)(ws + o_RB);                     // 3 x 1024 x 2048 u16 = 12.6 MB
    u16*  pw_s1   = (u16*)(ws + o_RB + (size_t)16 * 1024 * 1024);  // 3 x 256 x 1024 u16 = 1.6 MB
    float* qbuf   = (float*)(ws + o_RB);
    // region C: bufX -> yscan (in-place norm)
    float* bufX   = (float*)(ws + o_RC);
    float* yscan  = (float*)(ws + o_RC);

    // 0. init + in_w plane split (RA is dead until conv)
    zerod_kernel<<<1, 64, 0, stream>>>(ssum, 4);
    {
        long n = (long)DPROJ * 1024;
        split3_kernel<<<(n + 255) / 256, 256, 0, stream>>>(in_w, pw_in, n);
    }
    // 1. rmsnorm(x) -> u (stored in outy region of d_out)
    rms_x_kernel<<<ROWS, 256, 0, stream>>>(x, norm_w, outy);
    // 2. in_proj (6-term split, pre-split B): -> bufZ (z), bufX (xBC), dt/dA
    gemm_f32<3, 0, true><<<dim3(35, 64), 256, 0, stream>>>(outy, 1024, nullptr, 0,
                                                           pw_in, (size_t)DPROJ * 1024,
                                                           ROWS, DPROJ, 1024,
                                                           bufZ, bufX, dt_bias, A_log, dtb, dab);
    // 3. conv + silu (f64 math) -> xbc (R_A, over dead in_w planes)
    conv_kernel<<<Bb * 32 * 36, 256, 0, stream>>>(bufX, conv_w, conv_b, xbc);
    // 4. scan (8-deep pipelined register scan) -> yscan (R_C, over dead bufX)
    scan_kernel<<<Bb * NH * 4, 64, 0, stream>>>(xbc, dtb, dab, Dp, yscan);
    // 5. ssm rmsnorm (f64, in-place over yscan); bufZ dead after this
    ssmnorm_kernel<<<ROWS, 256, 0, stream>>>(yscan, bufZ, ssm_w);
    // 5b. out_w + s_w1 plane splits into dead R_B
    {
        long n = (long)1024 * 2048;
        split3_kernel<<<(n + 255) / 256, 256, 0, stream>>>(out_w, pw_out, n);
        long n2 = (long)256 * 1024;
        split3_kernel<<<(n2 + 255) / 256, 256, 0, stream>>>(s_w1, pw_s1, n2);
    }
    // 6. out_proj (6-term split, pre-split B) + residual -> outy, concat (R_A)
    gemm_f32<3, 2, true><<<dim3(8, 64), 256, 0, stream>>>(yscan, 2048, nullptr, 0,
                                                          pw_out, (size_t)1024 * 2048,
                                                          ROWS, 1024, 2048,
                                                          outy, concat, x, nullptr, nullptr, nullptr);
    // 7. score1 (6-term split, pre-split B, relu) -> sch
    gemm_f32<3, 1, true><<<dim3(2, 64), 256, 0, stream>>>(outy, 1024, nullptr, 0,
                                                          pw_s1, (size_t)256 * 1024,
                                                          ROWS, 256, 1024,
                                                          sch, nullptr, nullptr, nullptr, nullptr, nullptr);
    // 8. score2 (f64) -> scores, ssum
    score2_kernel<<<ROWS / 4, 256, 0, stream>>>(sch, s_w2, scores, ssum);
    // 9. top-64
    top64_kernel<<<Bb, 256, 0, stream>>>(scores, tidx, tval);
    // 10. summaries (f32 y, f64 accum)
    summ_kernel<<<Bb * 64, 256, 0, stream>>>(outy, tidx, summ_w, summ);
    // 11. pool update -> d_out pool/pri/counts + rmask
    pool_kernel<<<Bb, 256, 0, stream>>>(pool_in, pri_in, cnt_in, tval, summ, ssum,
                                        outpool, outpri, outcnt, rmk);
    // 12. k, v
    kv_kernel<<<Bb * 64, 256, 0, stream>>>(outpool, k_w, v_w, kbuf, vbuf);
    // 13. q = y @ q_w^T (plain bf16); qbuf overlays dead out_w planes
    gemm_f32<1, 3, false><<<dim3(2, 64), 256, 0, stream>>>(outy, 1024, q_w, 1024, nullptr, 0,
                                                           ROWS, 256, 1024,
                                                           qbuf, nullptr, nullptr, nullptr, nullptr, nullptr);
    // 14. attention -> retrieved (f32, concat second half)
    attn_kernel<<<ROWS, 256, 0, stream>>>(qbuf, kbuf, vbuf, outcnt, concat);
    // 15. gate GEMM (plain bf16) + final y update
    gemm_f32<1, 4, false><<<dim3(8, 64), 256, 0, stream>>>(concat, 2048, gate_w, 2048, nullptr, 0,
                                                           ROWS, 1024, 2048,
                                                           outy, nullptr, concat, rmk, nullptr, nullptr);
}

// Round 6
// 2354.947 us; speedup vs baseline: 1.2960x; 1.1502x over previous
//
#include <hip/hip_runtime.h>

// ---------------------------------------------------------------------------
// MemMambaBlock on MI355X.  B=4 T=2048 D=1024 D_INNER=2048 D_STATE=128
// NHEADS=32 HEADDIM=64 D_CONV=4 POOL=64 SUMDIM=256 d_in_proj=4384
// Precision: 6-term 3-way-bf16-split MFMA (~f32-exact) for in_proj/out_proj/
// score1; f64 conv/norms/score head; plain bf16 MFMA q/gate.
// Scan v5: producer/consumer 2-wave block.  Producer = global_load_lds DMA
// ring (8 slots, 6 ahead) + counted vmcnt(10) + raw s_barrier (loads stay in
// flight across barriers).  Consumer = R5-bitwise-identical math (same lane
// ownership, same fmaf chains) reading the LDS ring — zero reliance on
// compiler software pipelining (R4/R5 showed it de-pipelines register rings).
// ---------------------------------------------------------------------------

using u16 = unsigned short;
using bf16x8 = __attribute__((ext_vector_type(8))) short;
using f32x4  = __attribute__((ext_vector_type(4))) float;

#define DEV __device__ __forceinline__

#define GLOAD4(g, l)  __builtin_amdgcn_global_load_lds((const __attribute__((address_space(1))) void*)(g), (__attribute__((address_space(3))) void*)(l), 4, 0, 0)
#define GLOAD16(g, l) __builtin_amdgcn_global_load_lds((const __attribute__((address_space(1))) void*)(g), (__attribute__((address_space(3))) void*)(l), 16, 0, 0)

static constexpr int Bb = 4, T = 2048, D = 1024;
static constexpr int DIN = 2048, DST = 128, NH = 32;
static constexpr int DPROJ = 4384;          // 2*DIN + 2*DST + NH
static constexpr int CCH = 2304;            // DIN + 2*DST (conv channels)
static constexpr int ROWS = Bb * T;         // 8192

DEV float bf2f(u16 h) { union { unsigned int u; float f; } v; v.u = ((unsigned int)h) << 16; return v.f; }
DEV u16 f2bf(float f) { union { float f; unsigned int u; } v; v.f = f; unsigned int r = v.u + 0x7fffu + ((v.u >> 16) & 1u); return (u16)(r >> 16); }
DEV double sigd(double x) { return 1.0 / (1.0 + exp(-x)); }

__global__ void diag_kernel(float* o, float v) { if (threadIdx.x == 0) o[0] = v; }
__global__ void zerod_kernel(double* p, int n) { if ((int)threadIdx.x < n) p[threadIdx.x] = 0.0; }

// --------------------------------------------- 3-plane bf16 weight split
__global__ void split3_kernel(const float* __restrict__ in, u16* __restrict__ out, long n) {
    long i = (long)blockIdx.x * 256 + threadIdx.x;
    if (i >= n) return;
    float v = in[i];
    u16 h = f2bf(v);
    float r1 = v - bf2f(h);
    u16 m = f2bf(r1);
    out[i] = h;
    out[n + i] = m;
    out[2 * n + i] = f2bf(r1 - bf2f(m));
}

// ------------------------------------------------------------- rmsnorm(x)
__global__ __launch_bounds__(256) void rms_x_kernel(const float* __restrict__ x, const float* __restrict__ w,
                                                    float* __restrict__ u) {
    long row = blockIdx.x; int tid = threadIdx.x;
    const float* xr = x + row * D;
    float4 xv = *(const float4*)(xr + tid * 4);
    double ss = (double)xv.x * xv.x + (double)xv.y * xv.y + (double)xv.z * xv.z + (double)xv.w * xv.w;
    for (int off = 1; off < 64; off <<= 1) ss += __shfl_xor(ss, off);
    __shared__ double tmp[4];
    if ((tid & 63) == 0) tmp[tid >> 6] = ss;
    __syncthreads();
    double tot = tmp[0] + tmp[1] + tmp[2] + tmp[3];
    double scale = 1.0 / sqrt(tot / (double)D + 1e-4);
    float4 wv = *(const float4*)(w + tid * 4);
    long base = row * D + tid * 4;
    u[base + 0] = (float)((double)xv.x * scale * (double)wv.x);
    u[base + 1] = (float)((double)xv.y * scale * (double)wv.y);
    u[base + 2] = (float)((double)xv.z * scale * (double)wv.z);
    u[base + 3] = (float)((double)xv.w * scale * (double)wv.w);
}

// ----------------------------------------------------------------- GEMM
template <int NP>
DEV void stage_one(u16* s0, u16* s1, u16* s2, const float* __restrict__ src, long ld,
                   int row0, int lastrow, int k0, int tid) {
    int r = tid >> 1, c0 = (tid & 1) << 4;
    long rg = row0 + r; if (rg > lastrow) rg = lastrow;
    const float* p = src + rg * ld + k0 + c0;
    int base = r * 32 + c0;
#pragma unroll
    for (int q = 0; q < 4; q++) {
        float4 v4 = *(const float4*)(p + q * 4);
        float vv[4] = { v4.x, v4.y, v4.z, v4.w };
#pragma unroll
        for (int j = 0; j < 4; j++) {
            float xv = vv[j];
            u16 h = f2bf(xv);
            s0[base + q * 4 + j] = h;
            if constexpr (NP == 3) {
                float r1 = xv - bf2f(h);
                u16 m = f2bf(r1);
                s1[base + q * 4 + j] = m;
                float r2 = r1 - bf2f(m);
                s2[base + q * 4 + j] = f2bf(r2);
            }
        }
    }
}

DEV void stage_pre(u16* dst, const u16* __restrict__ src, long ld, int row0, int lastrow, int k0, int tid) {
    int r = tid >> 1, c = (tid & 1) << 4;
    long rg = row0 + r; if (rg > lastrow) rg = lastrow;
    const u16* p = src + rg * ld + k0 + c;
    *(uint4*)(dst + r * 32 + c)     = *(const uint4*)p;
    *(uint4*)(dst + r * 32 + c + 8) = *(const uint4*)(p + 8);
}

template <int NP, int MODE, bool BP>
__global__ __launch_bounds__(256) void gemm_f32(
    const float* __restrict__ A, long lda,
    const float* __restrict__ B, long ldb,
    const u16* __restrict__ Bp, size_t bstride,
    int M, int N, int K,
    float* __restrict__ out0, float* __restrict__ out1,
    const float* __restrict__ aux0, const float* __restrict__ aux1,
    float* __restrict__ dtb, float* __restrict__ dab) {
    __shared__ __align__(16) u16 sm[NP * 2 * 4096];
    u16* As[3]; u16* Bs[3];
#pragma unroll
    for (int p = 0; p < NP; p++) { As[p] = sm + p * 4096; Bs[p] = sm + (NP + p) * 4096; }
    int tid = threadIdx.x, lane = tid & 63, wid = tid >> 6;
    int wr = wid >> 1, wc = wid & 1;
    int tM = blockIdx.y * 128, tN = blockIdx.x * 128;

    f32x4 acc[4][4];
#pragma unroll
    for (int i = 0; i < 4; i++)
#pragma unroll
        for (int j = 0; j < 4; j++) acc[i][j] = f32x4{0.f, 0.f, 0.f, 0.f};

    int nsteps = K / 32;
    for (int kt = 0; kt < nsteps; ++kt) {
        int k0 = kt * 32;
        __syncthreads();
        stage_one<NP>(As[0], NP == 3 ? As[1] : nullptr, NP == 3 ? As[2] : nullptr, A, lda, tM, M - 1, k0, tid);
        if constexpr (BP) {
#pragma unroll
            for (int p = 0; p < NP; p++)
                stage_pre(Bs[p], Bp + (size_t)p * bstride, K, tN, N - 1, k0, tid);
        } else {
            stage_one<NP>(Bs[0], NP == 3 ? Bs[1] : nullptr, NP == 3 ? Bs[2] : nullptr, B, ldb, tN, N - 1, k0, tid);
        }
        __syncthreads();
        int rA = wr * 64 + (lane & 15);
        int rB = wc * 64 + (lane & 15);
        int kk = (lane >> 4) * 8;
        bf16x8 af[NP][4], bfr[NP][4];
#pragma unroll
        for (int p = 0; p < NP; p++)
#pragma unroll
            for (int i = 0; i < 4; i++) {
                af[p][i]  = *(const bf16x8*)(As[p] + (rA + i * 16) * 32 + kk);
                bfr[p][i] = *(const bf16x8*)(Bs[p] + (rB + i * 16) * 32 + kk);
            }
#pragma unroll
        for (int mi = 0; mi < 4; mi++)
#pragma unroll
            for (int ni = 0; ni < 4; ni++) {
                acc[mi][ni] = __builtin_amdgcn_mfma_f32_16x16x32_bf16(af[0][mi], bfr[0][ni], acc[mi][ni], 0, 0, 0);
                if constexpr (NP == 3) {
                    acc[mi][ni] = __builtin_amdgcn_mfma_f32_16x16x32_bf16(af[0][mi], bfr[1][ni], acc[mi][ni], 0, 0, 0);
                    acc[mi][ni] = __builtin_amdgcn_mfma_f32_16x16x32_bf16(af[1][mi], bfr[0][ni], acc[mi][ni], 0, 0, 0);
                    acc[mi][ni] = __builtin_amdgcn_mfma_f32_16x16x32_bf16(af[0][mi], bfr[2][ni], acc[mi][ni], 0, 0, 0);
                    acc[mi][ni] = __builtin_amdgcn_mfma_f32_16x16x32_bf16(af[1][mi], bfr[1][ni], acc[mi][ni], 0, 0, 0);
                    acc[mi][ni] = __builtin_amdgcn_mfma_f32_16x16x32_bf16(af[2][mi], bfr[0][ni], acc[mi][ni], 0, 0, 0);
                }
            }
    }
    int laneh = lane >> 4, lanel = lane & 15;
#pragma unroll
    for (int mi = 0; mi < 4; mi++)
#pragma unroll
        for (int ni = 0; ni < 4; ni++) {
            int col = tN + wc * 64 + ni * 16 + lanel;
            if (col >= N) continue;
#pragma unroll
            for (int r = 0; r < 4; r++) {
                long row = tM + wr * 64 + mi * 16 + laneh * 4 + r;
                float v = acc[mi][ni][r];
                if constexpr (MODE == 0) {
                    if (col < 2048) out0[row * 2048 + col] = v;
                    else if (col < 4352) out1[row * 2304 + (col - 2048)] = v;
                    else {
                        int h = col - 4352;
                        double xx = (double)v + (double)aux0[h];
                        double sp = (xx > 30.0) ? xx : log1p(exp(xx));
                        double a = -exp((double)aux1[h]);
                        dtb[row * NH + h] = (float)sp;
                        dab[row * NH + h] = (float)exp(sp * a);
                    }
                } else if constexpr (MODE == 1) {
                    out0[row * 256 + col] = fmaxf(v, 0.f);
                } else if constexpr (MODE == 2) {
                    float y = aux0[row * 1024 + col] + v;
                    out0[row * 1024 + col] = y;
                    out1[row * 2048 + col] = y;
                } else if constexpr (MODE == 3) {
                    out0[row * 256 + col] = v;
                } else {
                    double g = sigd((double)v);
                    float retr = aux0[row * 2048 + 1024 + col];
                    out0[row * 1024 + col] += (float)(g * (double)retr * (double)aux1[row >> 11]);
                }
            }
        }
}

// ------------------------------------------------- depthwise causal conv4
__global__ __launch_bounds__(256) void conv_kernel(const float* __restrict__ xin, const float* __restrict__ cw,
                                                   const float* __restrict__ cb, float* __restrict__ xbc) {
    int blk = blockIdx.x;
    int ct = blk % 36; int tt = (blk / 36) % 32; int b = blk / (36 * 32);
    int c0 = ct * 64, t0 = tt * 64;
    int tid = threadIdx.x;
    __shared__ float tile[67 * 64];
    for (int i = tid; i < 67 * 64; i += 256) {
        int r = i >> 6, c = i & 63;
        int t = t0 - 3 + r;
        tile[i] = (t >= 0) ? xin[((long)(b * T + t)) * CCH + c0 + c] : 0.f;
    }
    __syncthreads();
    int c = tid & 63; int rb = (tid >> 6) * 16;
    int gc = c0 + c;
    double w0 = cw[gc * 4], w1 = cw[gc * 4 + 1], w2 = cw[gc * 4 + 2], w3 = cw[gc * 4 + 3];
    double bias = cb[gc];
    for (int j = 0; j < 16; j++) {
        int tl = rb + j;
        double a = bias + w0 * (double)tile[tl * 64 + c] + w1 * (double)tile[(tl + 1) * 64 + c]
                        + w2 * (double)tile[(tl + 2) * 64 + c] + w3 * (double)tile[(tl + 3) * 64 + c];
        xbc[((long)(b * T + t0 + tl)) * CCH + gc] = (float)(a * sigd(a));
    }
}

// ------------------------------------------------------------- SSM scan v5
// 512 blocks x 128 threads.  Wave 0 = consumer (R5-bitwise-identical math),
// wave 1 = producer (global_load_lds DMA, 8-slot ring, 6 steps ahead,
// vmcnt(10) counted wait, raw s_barrier so DMAs stay in flight).
__global__ __launch_bounds__(128) void scan_kernel(const float* __restrict__ xbc, const float* __restrict__ dtb,
                                                   const float* __restrict__ dab, const float* __restrict__ Dp,
                                                   float* __restrict__ ys) {
    int bx = blockIdx.x;
    int b = bx >> 7, h = (bx >> 2) & 31, q = bx & 3;
    int tid = threadIdx.x;
    int wid = tid >> 6, l = tid & 63;
    __shared__ __align__(16) float sbc[8][256];   // slot: B[0..127] || C[128..255]
    __shared__ __align__(16) float sx[8][256];    // slot: x[0..15] used (DMA fills 1KB)
    __shared__ float sdt[T];
    __shared__ float sda[T];
    long rowbase = (long)b * T;

    if (wid == 1) {
        // ---------------- producer ----------------
        const float* bcrow = xbc + rowbase * CCH + 2048;
        const float* xrow  = xbc + rowbase * CCH + h * 64 + q * 16;
        // dt/dA full preload (gather: lane l -> step i*64+l)
        for (int i = 0; i < 32; i++) {
            GLOAD4(dtb + (rowbase + i * 64 + l) * NH + h, &sdt[i * 64]);
            GLOAD4(dab + (rowbase + i * 64 + l) * NH + h, &sda[i * 64]);
        }
        // ring prologue: steps 0..5
        for (int s = 0; s < 6; s++) {
            GLOAD16(bcrow + (long)s * CCH + l * 4, &sbc[s][0]);
            GLOAD16(xrow + (long)s * CCH + (l & 3) * 4, &sx[s][0]);
        }
        asm volatile("s_waitcnt vmcnt(10)" ::: "memory");
        __builtin_amdgcn_s_barrier();
        for (int t = 0; t < T; t++) {
            int s = t + 6;
            if (s < T) {
                int slot = s & 7;
                GLOAD16(bcrow + (long)s * CCH + l * 4, &sbc[slot][0]);
                GLOAD16(xrow + (long)s * CCH + (l & 3) * 4, &sx[slot][0]);
                asm volatile("s_waitcnt vmcnt(10)" ::: "memory");
            } else {
                asm volatile("s_waitcnt vmcnt(0)" ::: "memory");
            }
            __builtin_amdgcn_s_barrier();
        }
    } else {
        // ---------------- consumer (math identical to R5 scan) ----------------
        int pl = l >> 2, sub = l & 3;
        float hs[32];
#pragma unroll
        for (int j = 0; j < 32; j++) hs[j] = 0.f;
        float sDp = Dp[h];
        float* yout = ys + rowbase * DIN + h * 64 + q * 16 + pl;
        __builtin_amdgcn_s_barrier();
        __builtin_amdgcn_sched_barrier(0);
        for (int t = 0; t < T; t++) {
            int slot = t & 7;
            float xt = sx[slot][pl];
            float dtx = sdt[t] * xt;
            float dac = sda[t];
            const float4* bp = (const float4*)&sbc[slot][0];
            float y0 = 0.f, y1 = 0.f, y2 = 0.f, y3 = 0.f;
#pragma unroll
            for (int g = 0; g < 8; g++) {
                float4 bv = bp[sub * 8 + g];
                float4 cv = bp[32 + sub * 8 + g];
                hs[g * 4 + 0] = fmaf(dac, hs[g * 4 + 0], dtx * bv.x); y0 = fmaf(hs[g * 4 + 0], cv.x, y0);
                hs[g * 4 + 1] = fmaf(dac, hs[g * 4 + 1], dtx * bv.y); y1 = fmaf(hs[g * 4 + 1], cv.y, y1);
                hs[g * 4 + 2] = fmaf(dac, hs[g * 4 + 2], dtx * bv.z); y2 = fmaf(hs[g * 4 + 2], cv.z, y2);
                hs[g * 4 + 3] = fmaf(dac, hs[g * 4 + 3], dtx * bv.w); y3 = fmaf(hs[g * 4 + 3], cv.w, y3);
            }
            float y = (y0 + y1) + (y2 + y3);
            y += __shfl_xor(y, 1);
            y += __shfl_xor(y, 2);
            if (sub == 0) yout[(long)t * DIN] = y + sDp * xt;
            __builtin_amdgcn_sched_barrier(0);
            __builtin_amdgcn_s_barrier();
            __builtin_amdgcn_sched_barrier(0);
        }
    }
}

// -------------------------------------------- rmsnorm(y_scan * silu(z)), in-place
__global__ __launch_bounds__(256) void ssmnorm_kernel(float* __restrict__ ys, const float* __restrict__ z,
                                                      const float* __restrict__ w) {
    long row = blockIdx.x; int tid = threadIdx.x;
    float* yr = ys + row * DIN;
    const float* zr = z + row * DIN;
    double v[8]; double ss = 0.0;
#pragma unroll
    for (int j = 0; j < 8; j++) {
        int c = tid * 8 + j;
        double zz = (double)zr[c];
        double val = (double)yr[c] * (zz * sigd(zz));
        v[j] = val; ss += val * val;
    }
    for (int off = 1; off < 64; off <<= 1) ss += __shfl_xor(ss, off);
    __shared__ double tmp[4];
    if ((tid & 63) == 0) tmp[tid >> 6] = ss;
    __syncthreads();
    double tot = tmp[0] + tmp[1] + tmp[2] + tmp[3];
    double scale = 1.0 / sqrt(tot / (double)DIN + 1e-5);
#pragma unroll
    for (int j = 0; j < 8; j++) {
        int c = tid * 8 + j;
        yr[c] = (float)(v[j] * scale * (double)w[c]);
    }
}

// ------------------------------------------------------- score head (2)
__global__ void score2_kernel(const float* __restrict__ sh, const float* __restrict__ w2,
                              float* __restrict__ scores, double* __restrict__ ssum) {
    int row = blockIdx.x * 4 + (threadIdx.x >> 6);
    int lane = threadIdx.x & 63;
    const float* h = sh + (long)row * 256;
    double a = 0.0;
    for (int j = 0; j < 4; j++) a += (double)h[lane * 4 + j] * (double)w2[lane * 4 + j];
    for (int off = 1; off < 64; off <<= 1) a += __shfl_xor(a, off);
    if (lane == 0) {
        double sc = sigd(a);
        scores[row] = (float)sc;
        atomicAdd(&ssum[row >> 11], sc);
    }
}

// ------------------------------------------------ top-64 (stable argsort)
__global__ void top64_kernel(const float* __restrict__ scores, int* __restrict__ tidx, float* __restrict__ tval) {
    int b = blockIdx.x; int tid = threadIdx.x;
    __shared__ float s[T];
    __shared__ float rv[256];
    __shared__ int ri[256];
    for (int i = tid; i < T; i += 256) s[i] = scores[b * T + i];
    for (int k = 0; k < 64; k++) {
        __syncthreads();
        float best = -1e30f; int bi = 1 << 30;
        for (int i = tid; i < T; i += 256) {
            float v = s[i];
            if (v > best || (v == best && i < bi)) { best = v; bi = i; }
        }
        rv[tid] = best; ri[tid] = bi;
        __syncthreads();
        for (int off = 128; off > 0; off >>= 1) {
            if (tid < off) {
                float v2 = rv[tid + off]; int i2 = ri[tid + off];
                if (v2 > rv[tid] || (v2 == rv[tid] && i2 < ri[tid])) { rv[tid] = v2; ri[tid] = i2; }
            }
            __syncthreads();
        }
        if (tid == 0) { tidx[b * 64 + k] = ri[0]; tval[b * 64 + k] = rv[0]; s[ri[0]] = -1e30f; }
    }
}

// ---------------------------------------------------- summaries (64/b)
__global__ __launch_bounds__(256) void summ_kernel(const float* __restrict__ y, const int* __restrict__ tidx,
                                                   const float* __restrict__ wsum, float* __restrict__ summ) {
    int s = blockIdx.x & 63; int b = blockIdx.x >> 6;
    int tid = threadIdx.x;
    __shared__ float yrow[1024];
    int tok = tidx[b * 64 + s];
    long base = ((long)(b * T + tok));
    for (int i = tid; i < 1024; i += 256) yrow[i] = y[base * 1024 + i];
    __syncthreads();
    double acc = 0.0;
    const float* w = wsum + (long)tid * 1024;
    for (int kk = 0; kk < 1024; kk++) acc += (double)yrow[kk] * (double)w[kk];
    summ[((long)(b * 64 + s)) * 256 + tid] = (float)acc;
}

// -------------------------------------------------------- pool update
__global__ void pool_kernel(const float* __restrict__ pin, const float* __restrict__ prin,
                            const int* __restrict__ cin, const float* __restrict__ tval,
                            const float* __restrict__ summ, const double* __restrict__ ssum,
                            float* __restrict__ pout, float* __restrict__ prout,
                            float* __restrict__ cout, float* __restrict__ rmask) {
    int b = blockIdx.x; int tid = threadIdx.x;
    __shared__ float spri[64];
    __shared__ int scount, sact, sslot, srep, srslot;
    for (int i = tid; i < 64 * 256; i += 256) pout[(long)b * 16384 + i] = pin[(long)b * 16384 + i];
    if (tid < 64) spri[tid] = prin[b * 64 + tid];
    if (tid == 0) scount = cin[b];
    __syncthreads();
    for (int s = 0; s < 64; s++) {
        float imp = tval[b * 64 + s];
        bool has = imp > 0.5f;                       // TAU1
        if (tid == 0) {
            sact = 0;
            if (has && scount < 64) { sslot = scount; spri[scount] = imp; scount++; sact = 1; }
        }
        __syncthreads();
        if (sact) pout[((long)(b * 64 + sslot)) * 256 + tid] = summ[((long)(b * 64 + s)) * 256 + tid];
        if (tid < 64) {
            float v = spri[tid]; int idx = tid;
            for (int off = 1; off < 64; off <<= 1) {
                float v2 = __shfl_xor(v, off); int i2 = __shfl_xor(idx, off);
                if (v2 < v || (v2 == v && i2 < idx)) { v = v2; idx = i2; }
            }
            if (tid == 0) {
                srep = 0;
                if (has && scount >= 64 && imp > v) { srep = 1; srslot = idx; spri[idx] = imp; }
            }
        }
        __syncthreads();
        if (srep) pout[((long)(b * 64 + srslot)) * 256 + tid] = summ[((long)(b * 64 + s)) * 256 + tid];
        __syncthreads();
    }
    if (tid < 64) prout[b * 64 + tid] = spri[tid];
    if (tid == 0) {
        cout[b] = (float)scount;
        double mean = ssum[b] / (double)T;
        rmask[b] = (mean > 0.4 && scount > 0) ? 1.f : 0.f;
    }
}

// ------------------------------------------------------------ k,v proj
__global__ __launch_bounds__(256) void kv_kernel(const float* __restrict__ pool, const float* __restrict__ kw,
                                                 const float* __restrict__ vw, float* __restrict__ k,
                                                 float* __restrict__ v) {
    int blk = blockIdx.x; int b = blk >> 6, s = blk & 63; int tid = threadIdx.x;
    __shared__ float pr[256];
    pr[tid] = pool[((long)(b * 64 + s)) * 256 + tid];
    __syncthreads();
    float a = 0.f;
    const float* w = kw + (long)tid * 256;
    for (int j = 0; j < 256; j++) a = fmaf(pr[j], w[j], a);
    k[((long)(b * 64 + s)) * 256 + tid] = a;
    for (int m = 0; m < 4; m++) {
        int o = m * 256 + tid;
        const float* w2 = vw + (long)o * 256;
        float c = 0.f;
        for (int j = 0; j < 256; j++) c = fmaf(pr[j], w2[j], c);
        v[((long)(b * 64 + s)) * 1024 + o] = c;
    }
}

// ----------------------------------------------------- pool attention
__global__ __launch_bounds__(256) void attn_kernel(const float* __restrict__ q, const float* __restrict__ k,
                                                   const float* __restrict__ v, const float* __restrict__ cout,
                                                   float* __restrict__ concat) {
    long row = blockIdx.x;
    int b = (int)(row >> 11);
    int tid = threadIdx.x;
    int cnt = (int)cout[b];
    __shared__ float qs[256], slog[64], sp[64];
    qs[tid] = q[row * 256 + tid];
    __syncthreads();
    int s = tid >> 2, part = tid & 3;
    const float* kr = k + ((long)(b * 64 + s)) * 256 + part * 64;
    float d = 0.f;
    for (int j = 0; j < 64; j++) d = fmaf(qs[part * 64 + j], kr[j], d);
    d += __shfl_xor(d, 1); d += __shfl_xor(d, 2);
    if (part == 0) slog[s] = d * 0.0625f;
    __syncthreads();
    if (tid < 64) {
        float l = (tid < cnt) ? slog[tid] : -1e30f;
        float m = l;
        for (int off = 1; off < 64; off <<= 1) m = fmaxf(m, __shfl_xor(m, off));
        float e = (tid < cnt) ? expf(l - m) : 0.f;
        float su = e;
        for (int off = 1; off < 64; off <<= 1) su += __shfl_xor(su, off);
        sp[tid] = (cnt > 0) ? e / su : 0.f;
    }
    __syncthreads();
    float acc[4] = {0.f, 0.f, 0.f, 0.f};
    for (int s2 = 0; s2 < cnt; s2++) {
        float p = sp[s2];
        const float* vr = v + ((long)(b * 64 + s2)) * 1024 + tid;
        acc[0] = fmaf(p, vr[0], acc[0]);
        acc[1] = fmaf(p, vr[256], acc[1]);
        acc[2] = fmaf(p, vr[512], acc[2]);
        acc[3] = fmaf(p, vr[768], acc[3]);
    }
    for (int j = 0; j < 4; j++) concat[row * 2048 + 1024 + tid + j * 256] = acc[j];
}

// ===========================================================================
extern "C" void kernel_launch(void* const* d_in, const int* in_sizes, int n_in,
                              void* d_out, int out_size, void* d_ws, size_t ws_size,
                              hipStream_t stream) {
    (void)in_sizes; (void)n_in; (void)out_size;
    const float* x       = (const float*)d_in[0];
    const float* pool_in = (const float*)d_in[1];
    const float* pri_in  = (const float*)d_in[2];
    const int*   cnt_in  = (const int*)d_in[3];
    const float* norm_w  = (const float*)d_in[4];
    const float* in_w    = (const float*)d_in[5];
    const float* conv_w  = (const float*)d_in[6];
    const float* conv_b  = (const float*)d_in[7];
    const float* dt_bias = (const float*)d_in[8];
    const float* A_log   = (const float*)d_in[9];
    const float* Dp      = (const float*)d_in[10];
    const float* ssm_w   = (const float*)d_in[11];
    const float* out_w   = (const float*)d_in[12];
    const float* s_w1    = (const float*)d_in[13];
    const float* s_w2    = (const float*)d_in[14];
    const float* summ_w  = (const float*)d_in[15];
    const float* q_w     = (const float*)d_in[16];
    const float* k_w     = (const float*)d_in[17];
    const float* v_w     = (const float*)d_in[18];
    const float* gate_w  = (const float*)d_in[19];

    float* outy    = (float*)d_out;
    float* outpool = outy + (long)ROWS * D;
    float* outpri  = outpool + Bb * 64 * 256;
    float* outcnt  = outpri + Bb * 64;

    char* ws = (char*)d_ws;
    size_t cur = 0;
    auto alloc = [&](size_t bytes) { size_t o = cur; cur += (bytes + 255) / 256 * 256; return o; };

    size_t o_dt   = alloc((size_t)ROWS * NH * 4);
    size_t o_da   = alloc((size_t)ROWS * NH * 4);
    size_t o_sc   = alloc((size_t)ROWS * 4);
    size_t o_ssum = alloc(64);
    size_t o_rmk  = alloc(64);
    size_t o_tidx = alloc(Bb * 64 * 4);
    size_t o_tval = alloc(Bb * 64 * 4);
    size_t o_summ = alloc((size_t)Bb * 64 * 256 * 4);
    size_t o_k    = alloc((size_t)Bb * 64 * 256 * 4);
    size_t o_v    = alloc((size_t)Bb * 64 * 1024 * 4);
    size_t o_RA = alloc((size_t)ROWS * CCH * 4);   // in_w planes -> xbc -> concat+sch
    size_t o_RB = alloc((size_t)ROWS * DIN * 4);   // bufZ -> out_w/s_w1 planes -> qbuf
    size_t o_RC = alloc((size_t)ROWS * CCH * 4);   // bufX -> yscan/normed (in-place)

    if (ws_size < cur) {   // diagnostic: report ws_size in MB via absmax
        diag_kernel<<<1, 64, 0, stream>>>(outy, 1000.0f + (float)(ws_size >> 20));
        return;
    }

    float* dtb    = (float*)(ws + o_dt);
    float* dab    = (float*)(ws + o_da);
    float* scores = (float*)(ws + o_sc);
    double* ssum  = (double*)(ws + o_ssum);
    float* rmk    = (float*)(ws + o_rmk);
    int*   tidx   = (int*)(ws + o_tidx);
    float* tval   = (float*)(ws + o_tval);
    float* summ   = (float*)(ws + o_summ);
    float* kbuf   = (float*)(ws + o_k);
    float* vbuf   = (float*)(ws + o_v);

    // region A: in_w planes (dead before conv) -> xbc -> concat + sch
    u16*  pw_in   = (u16*)(ws + o_RA);
    float* xbc    = (float*)(ws + o_RA);
    float* concat = (float*)(ws + o_RA);
    float* sch    = (float*)(ws + o_RA + (size_t)ROWS * DIN * 4);
    // region B: bufZ -> {out_w planes, s_w1 planes} -> qbuf
    float* bufZ   = (float*)(ws + o_RB);
    u16*  pw_out  = (u16*)(ws + o_RB);
    u16*  pw_s1   = (u16*)(ws + o_RB + (size_t)16 * 1024 * 1024);
    float* qbuf   = (float*)(ws + o_RB);
    // region C: bufX -> yscan (in-place norm)
    float* bufX   = (float*)(ws + o_RC);
    float* yscan  = (float*)(ws + o_RC);

    // 0. init + in_w plane split (RA is dead until conv)
    zerod_kernel<<<1, 64, 0, stream>>>(ssum, 4);
    {
        long n = (long)DPROJ * 1024;
        split3_kernel<<<(n + 255) / 256, 256, 0, stream>>>(in_w, pw_in, n);
    }
    // 1. rmsnorm(x) -> u (stored in outy region of d_out)
    rms_x_kernel<<<ROWS, 256, 0, stream>>>(x, norm_w, outy);
    // 2. in_proj (6-term split, pre-split B): -> bufZ (z), bufX (xBC), dt/dA
    gemm_f32<3, 0, true><<<dim3(35, 64), 256, 0, stream>>>(outy, 1024, nullptr, 0,
                                                           pw_in, (size_t)DPROJ * 1024,
                                                           ROWS, DPROJ, 1024,
                                                           bufZ, bufX, dt_bias, A_log, dtb, dab);
    // 3. conv + silu (f64 math) -> xbc (R_A, over dead in_w planes)
    conv_kernel<<<Bb * 32 * 36, 256, 0, stream>>>(bufX, conv_w, conv_b, xbc);
    // 4. scan v5 (producer/consumer DMA ring) -> yscan (R_C, over dead bufX)
    scan_kernel<<<Bb * NH * 4, 128, 0, stream>>>(xbc, dtb, dab, Dp, yscan);
    // 5. ssm rmsnorm (f64, in-place over yscan); bufZ dead after this
    ssmnorm_kernel<<<ROWS, 256, 0, stream>>>(yscan, bufZ, ssm_w);
    // 5b. out_w + s_w1 plane splits into dead R_B
    {
        long n = (long)1024 * 2048;
        split3_kernel<<<(n + 255) / 256, 256, 0, stream>>>(out_w, pw_out, n);
        long n2 = (long)256 * 1024;
        split3_kernel<<<(n2 + 255) / 256, 256, 0, stream>>>(s_w1, pw_s1, n2);
    }
    // 6. out_proj (6-term split, pre-split B) + residual -> outy, concat (R_A)
    gemm_f32<3, 2, true><<<dim3(8, 64), 256, 0, stream>>>(yscan, 2048, nullptr, 0,
                                                          pw_out, (size_t)1024 * 2048,
                                                          ROWS, 1024, 2048,
                                                          outy, concat, x, nullptr, nullptr, nullptr);
    // 7. score1 (6-term split, pre-split B, relu) -> sch
    gemm_f32<3, 1, true><<<dim3(2, 64), 256, 0, stream>>>(outy, 1024, nullptr, 0,
                                                          pw_s1, (size_t)256 * 1024,
                                                          ROWS, 256, 1024,
                                                          sch, nullptr, nullptr, nullptr, nullptr, nullptr);
    // 8. score2 (f64) -> scores, ssum
    score2_kernel<<<ROWS / 4, 256, 0, stream>>>(sch, s_w2, scores, ssum);
    // 9. top-64
    top64_kernel<<<Bb, 256, 0, stream>>>(scores, tidx, tval);
    // 10. summaries (f32 y, f64 accum)
    summ_kernel<<<Bb * 64, 256, 0, stream>>>(outy, tidx, summ_w, summ);
    // 11. pool update -> d_out pool/pri/counts + rmask
    pool_kernel<<<Bb, 256, 0, stream>>>(pool_in, pri_in, cnt_in, tval, summ, ssum,
                                        outpool, outpri, outcnt, rmk);
    // 12. k, v
    kv_kernel<<<Bb * 64, 256, 0, stream>>>(outpool, k_w, v_w, kbuf, vbuf);
    // 13. q = y @ q_w^T (plain bf16); qbuf overlays dead out_w planes
    gemm_f32<1, 3, false><<<dim3(2, 64), 256, 0, stream>>>(outy, 1024, q_w, 1024, nullptr, 0,
                                                           ROWS, 256, 1024,
                                                           qbuf, nullptr, nullptr, nullptr, nullptr, nullptr);
    // 14. attention -> retrieved (f32, concat second half)
    attn_kernel<<<ROWS, 256, 0, stream>>>(qbuf, kbuf, vbuf, outcnt, concat);
    // 15. gate GEMM (plain bf16) + final y update
    gemm_f32<1, 4, false><<<dim3(8, 64), 256, 0, stream>>>(concat, 2048, gate_w, 2048, nullptr, 0,
                                                           ROWS, 1024, 2048,
                                                           outy, nullptr, concat, rmk, nullptr, nullptr);
}